// Round 3
// baseline (622.915 us; speedup 1.0000x reference)
//
#include <hip/hip_runtime.h>

typedef __attribute__((ext_vector_type(8))) short short8;
typedef __attribute__((ext_vector_type(4))) float floatx4;

#define B_ 2
#define S_ 2048
#define E_ 2048
#define H_ 16
#define D_ 128

#define NEG_S  (-3.0e4f)
#define LOG2E  1.4426950408889634f

__device__ inline float bf2f(unsigned short u) {
    union { unsigned int i; float f; } v; v.i = ((unsigned int)u) << 16; return v.f;
}
__device__ inline unsigned short f2bf(float f) {
    union { float f; unsigned int i; } v; v.f = f;
    unsigned int r = v.i + 0x7FFFu + ((v.i >> 16) & 1u);
    return (unsigned short)(r >> 16);
}

// async global->LDS, 16B per lane. LDS dest is wave-uniform base + lane*16.
__device__ inline void gload_lds16(const void* g, void* l) {
    __builtin_amdgcn_global_load_lds((__attribute__((address_space(1))) void*)(void*)g,
                                     (__attribute__((address_space(3))) void*)l, 16, 0, 0);
}

// Precompute RoPE cos/sin tables: [S][D/2] fp32. 1 MB total.
__global__ void rope_tab(float* __restrict__ cosT, float* __restrict__ sinT) {
    int idx = blockIdx.x * 256 + threadIdx.x;   // 2048*64 entries
    int s = idx >> 6, j = idx & 63;
    float inv = exp2f(-(float)(2 * j) * (13.287712379549449f / 128.0f));
    float ang = (float)s * inv;
    cosT[idx] = cosf(ang);
    sinT[idx] = sinf(ang);
}

// fp32 -> bf16, 8 elems/thread, exact-sized grids.
__global__ __launch_bounds__(256) void cvt_bf16(const float* __restrict__ in,
                                                unsigned short* __restrict__ out, int n8) {
    int i = blockIdx.x * 256 + threadIdx.x;
    if (i >= n8) return;
    float4 f0 = *(const float4*)(in + (size_t)i * 8);
    float4 f1 = *(const float4*)(in + (size_t)i * 8 + 4);
    unsigned short u[8] = {f2bf(f0.x), f2bf(f0.y), f2bf(f0.z), f2bf(f0.w),
                           f2bf(f1.x), f2bf(f1.y), f2bf(f1.z), f2bf(f1.w)};
    *(uint4*)(out + (size_t)i * 8) = *(uint4*)u;
}

// out_k fp32 [B][H][S][D] -> Kr bf16 same layout, RoPE applied once.
__global__ __launch_bounds__(256) void prep_k(const float* __restrict__ K,
                                              unsigned short* __restrict__ Kr,
                                              const float* __restrict__ cosT,
                                              const float* __restrict__ sinT) {
    int idx = blockIdx.x * 256 + threadIdx.x;   // B*H*S*16 = 1,048,576
    int g = idx & 15;
    int s = (idx >> 4) & (S_ - 1);
    const float* src = K + (size_t)idx * 8;
    float4 f0 = *(const float4*)src;
    float4 f1 = *(const float4*)(src + 4);
    float xs[8] = {f0.x, f0.y, f0.z, f0.w, f1.x, f1.y, f1.z, f1.w};
    unsigned short u[8];
    int jb = g * 4;
#pragma unroll
    for (int i = 0; i < 4; i++) {
        float c = cosT[s * 64 + jb + i], sn = sinT[s * 64 + jb + i];
        float x1 = xs[2 * i], x2 = xs[2 * i + 1];
        u[2 * i]     = f2bf(x1 * c - x2 * sn);
        u[2 * i + 1] = f2bf(x1 * sn + x2 * c);
    }
    *(uint4*)(Kr + (size_t)idx * 8) = *(uint4*)u;
}

// out_v fp32 [B][H][S][D] -> Vt bf16 [B][H][D][S] (transposed via LDS).
__global__ __launch_bounds__(256) void prep_v(const float* __restrict__ V,
                                              unsigned short* __restrict__ Vt) {
    __shared__ unsigned short Ls[64][130];
    int bh = blockIdx.y;
    int s0 = blockIdx.x * 64;
    int t = threadIdx.x;
    const float* src = V + ((size_t)bh * S_ + s0) * D_;
#pragma unroll
    for (int it = 0; it < 4; it++) {
        int r = it * 16 + (t >> 4), d0 = (t & 15) * 8;
        float4 f0 = *(const float4*)&src[(size_t)r * D_ + d0];
        float4 f1 = *(const float4*)&src[(size_t)r * D_ + d0 + 4];
        unsigned short u[8] = {f2bf(f0.x), f2bf(f0.y), f2bf(f0.z), f2bf(f0.w),
                               f2bf(f1.x), f2bf(f1.y), f2bf(f1.z), f2bf(f1.w)};
#pragma unroll
        for (int i = 0; i < 8; i++) Ls[r][d0 + i] = u[i];
    }
    __syncthreads();
    unsigned short* dst = Vt + (size_t)bh * D_ * S_;
#pragma unroll
    for (int it = 0; it < 4; it++) {
        int d = it * 32 + (t >> 3), ss = (t & 7) * 8;
        unsigned short u[8];
#pragma unroll
        for (int i = 0; i < 8; i++) u[i] = Ls[ss + i][d];
        *(uint4*)&dst[(size_t)d * S_ + s0 + ss] = *(uint4*)u;
    }
}

// ---- m97-style 128x128-tile bf16 GEMM: C = A @ W^T (unchanged, verified).
__global__ __launch_bounds__(256) void gemm128(const unsigned short* __restrict__ A,
                                               const unsigned short* __restrict__ Bw,
                                               void* __restrict__ dst, int dstMode) {
    __shared__ __align__(16) unsigned short As[128][32];
    __shared__ __align__(16) unsigned short Bs[128][32];
    int t = threadIdx.x;
    int wave = t >> 6, lane = t & 63;
    int quad = lane >> 4, l16 = lane & 15;
    int wr = wave >> 1, wc = wave & 1;

    floatx4 acc[4][4];
#pragma unroll
    for (int m = 0; m < 4; m++)
#pragma unroll
        for (int n = 0; n < 4; n++) acc[m][n] = (floatx4)(0.f);

    int srow = lane >> 2;
    int sg = lane & 3;
    const size_t aRow0 = (size_t)blockIdx.x * 128;
    const size_t bRow0 = (size_t)blockIdx.y * 128;

    for (int k0 = 0; k0 < E_; k0 += 32) {
#pragma unroll
        for (int i = 0; i < 2; i++) {
            int lr = wave * 32 + i * 16 + srow;
            int gg = sg ^ ((lr >> 1) & 3);
            gload_lds16(A + (aRow0 + lr) * E_ + k0 + gg * 8, &As[wave * 32 + i * 16][0]);
            gload_lds16(Bw + (bRow0 + lr) * E_ + k0 + gg * 8, &Bs[wave * 32 + i * 16][0]);
        }
        __syncthreads();
        short8 af[4], bfr[4];
#pragma unroll
        for (int m = 0; m < 4; m++) {
            int r = wr * 64 + m * 16 + l16;
            af[m] = *(const short8*)((const char*)As + r * 64 + ((quad ^ ((r >> 1) & 3)) << 4));
        }
#pragma unroll
        for (int n = 0; n < 4; n++) {
            int r = wc * 64 + n * 16 + l16;
            bfr[n] = *(const short8*)((const char*)Bs + r * 64 + ((quad ^ ((r >> 1) & 3)) << 4));
        }
#pragma unroll
        for (int m = 0; m < 4; m++)
#pragma unroll
            for (int n = 0; n < 4; n++)
                acc[m][n] = __builtin_amdgcn_mfma_f32_16x16x32_bf16(af[m], bfr[n], acc[m][n], 0, 0, 0);
        __syncthreads();
    }
#pragma unroll
    for (int m = 0; m < 4; m++)
#pragma unroll
        for (int n = 0; n < 4; n++)
#pragma unroll
            for (int rr = 0; rr < 4; rr++) {
                int mg = (int)aRow0 + wr * 64 + m * 16 + quad * 4 + rr;
                int ng = (int)bRow0 + wc * 64 + n * 16 + l16;
                float val = acc[m][n][rr];
                if (dstMode == 0) {
                    ((float*)dst)[(size_t)mg * E_ + ng] = val;
                } else if (dstMode == 1) {
                    int b = mg >> 11, s = mg & 2047, h = ng >> 7, d = ng & 127;
                    ((float*)dst)[(((size_t)(b * H_ + h)) * S_ + s) * D_ + d] = val;
                } else {
                    ((unsigned short*)dst)[(size_t)mg * E_ + ng] = f2bf(val);
                }
            }
}

// ---- Flash attention v2: QBLK=128 per block (2 q-frags/wave), double-buffered
// K/V staging (prefetch at top of iter, drain at barrier). LDS 73KB ->
// 2 blocks/CU from the LDS limit; NO min-waves launch bound (a ",2" bound
// would cap VGPR at 128 < live state and force scratch spills - round-2 bug).
__global__ __launch_bounds__(256) void attn_fast2(const unsigned short* __restrict__ Qf,
                                                  const unsigned short* __restrict__ Kr,
                                                  const unsigned short* __restrict__ Vt,
                                                  const float* __restrict__ cosT,
                                                  const float* __restrict__ sinT,
                                                  unsigned short* __restrict__ Omid) {
    __shared__ __align__(16) unsigned short Ks[2][64][128];
    __shared__ __align__(16) unsigned short Vs[2][128][64];
    __shared__ __align__(16) unsigned short Ps[4][16][72];

    int t = threadIdx.x;
    int wave = t >> 6, lane = t & 63;
    int quad = lane >> 4, l16 = lane & 15;

    int orig = blockIdx.x;                 // 0..511
    int xcd = orig & 7, slot = orig >> 3;  // assume round-robin XCD assignment
    int G = xcd * 4 + (slot >> 4);         // 0..31: (h,b) group, 2 heads per XCD
    int h = G >> 1, b = G & 1;
    int qr = slot & 15;
    int qt = ((slot >> 5) & 1) ? (15 - qr) : qr;   // co-resident blocks get qt, 15-qt

    const unsigned short* Qb = Qf + (size_t)b * S_ * E_;
    const unsigned short* Kh = Kr + ((size_t)(b * H_ + h)) * S_ * D_;
    const unsigned short* Vh = Vt + ((size_t)(b * H_ + h)) * D_ * S_;

    // Q fragments, 2 per wave (rows qt*128 + f*64 + wave*16 + l16), roped.
    short8 qf[2][4];
#pragma unroll
    for (int f = 0; f < 2; f++) {
        int sq = qt * 128 + f * 64 + wave * 16 + l16;
#pragma unroll
        for (int ks = 0; ks < 4; ks++) {
            int d0 = ks * 32 + quad * 8;
            union { uint4 u4; unsigned short u[8]; } un;
            un.u4 = *(const uint4*)&Qb[(size_t)sq * E_ + h * D_ + d0];
#pragma unroll
            for (int i = 0; i < 4; i++) {
                int j = (d0 >> 1) + i;
                float c = cosT[sq * 64 + j], s = sinT[sq * 64 + j];
                float x1 = bf2f(un.u[2 * i]), x2 = bf2f(un.u[2 * i + 1]);
                un.u[2 * i] = f2bf(x1 * c - x2 * s);
                un.u[2 * i + 1] = f2bf(x1 * s + x2 * c);
            }
            qf[f][ks] = *(short8*)un.u;
        }
    }

    floatx4 O[2][8];
#pragma unroll
    for (int f = 0; f < 2; f++)
#pragma unroll
        for (int i = 0; i < 8; i++) O[f][i] = (floatx4)(0.f);
    float mrow[2][4], lrow[2][4];
#pragma unroll
    for (int f = 0; f < 2; f++)
#pragma unroll
        for (int r = 0; r < 4; r++) { mrow[f][r] = NEG_S; lrow[f][r] = 0.f; }

    const float scale = 0.08838834764831845f; // 1/sqrt(128)
    int NT = 2 * qt + 2;

#define STAGE(BUF, KT)                                                          \
    {                                                                           \
        _Pragma("unroll")                                                       \
        for (int i_ = 0; i_ < 4; i_++) {                                        \
            int r_ = wave * 16 + i_ * 4 + (lane >> 4);                          \
            int g_ = (lane & 15) ^ (r_ & 7);                                    \
            gload_lds16(&Kh[(size_t)((KT) * 64 + r_) * D_ + g_ * 8],            \
                        &Ks[BUF][wave * 16 + i_ * 4][0]);                       \
        }                                                                       \
        _Pragma("unroll")                                                       \
        for (int i_ = 0; i_ < 4; i_++) {                                        \
            int r_ = wave * 32 + i_ * 8 + (lane >> 3);                          \
            int g_ = (lane & 7) ^ (r_ & 7);                                     \
            gload_lds16(&Vh[(size_t)r_ * S_ + (KT) * 64 + g_ * 8],              \
                        &Vs[BUF][wave * 32 + i_ * 8][0]);                       \
        }                                                                       \
    }

    STAGE(0, 0);
    __syncthreads();

    for (int kt = 0; kt < NT; kt++) {
        int cur = kt & 1;
        if (kt + 1 < NT) STAGE(cur ^ 1, kt + 1);   // prefetch into other buffer

        // S = Q K^T for both fragments, shared K reads.
        floatx4 sc[2][4];
#pragma unroll
        for (int f = 0; f < 2; f++)
#pragma unroll
            for (int ct = 0; ct < 4; ct++) sc[f][ct] = (floatx4)(0.f);
        __builtin_amdgcn_s_setprio(1);
#pragma unroll
        for (int ks = 0; ks < 4; ks++) {
#pragma unroll
            for (int ct = 0; ct < 4; ct++) {
                int r = ct * 16 + l16;
                short8 kf = *(const short8*)((const char*)&Ks[cur][0][0] + r * 256 +
                                             ((((ks << 2) + quad) ^ (r & 7)) << 4));
                sc[0][ct] = __builtin_amdgcn_mfma_f32_16x16x32_bf16(qf[0][ks], kf, sc[0][ct], 0, 0, 0);
                sc[1][ct] = __builtin_amdgcn_mfma_f32_16x16x32_bf16(qf[1][ks], kf, sc[1][ct], 0, 0, 0);
            }
        }
        __builtin_amdgcn_s_setprio(0);

#pragma unroll
        for (int f = 0; f < 2; f++) {
            // scale + causal mask
            int rowbase = qt * 128 + f * 64 + wave * 16 + quad * 4;
#pragma unroll
            for (int ct = 0; ct < 4; ct++) {
                int col = kt * 64 + ct * 16 + l16;
#pragma unroll
                for (int rr = 0; rr < 4; rr++) {
                    float x = sc[f][ct][rr] * scale;
                    sc[f][ct][rr] = (col > rowbase + rr) ? NEG_S : x;
                }
            }
            // online softmax (row reduce across 16 lanes of each quad-row)
            float alpha[4];
#pragma unroll
            for (int rr = 0; rr < 4; rr++) {
                float mx = fmaxf(fmaxf(sc[f][0][rr], sc[f][1][rr]),
                                 fmaxf(sc[f][2][rr], sc[f][3][rr]));
                mx = fmaxf(mx, __shfl_xor(mx, 1));
                mx = fmaxf(mx, __shfl_xor(mx, 2));
                mx = fmaxf(mx, __shfl_xor(mx, 4));
                mx = fmaxf(mx, __shfl_xor(mx, 8));
                float mnew = fmaxf(mrow[f][rr], mx);
                alpha[rr] = exp2f((mrow[f][rr] - mnew) * LOG2E);
                mrow[f][rr] = mnew;
            }
#pragma unroll
            for (int rr = 0; rr < 4; rr++) {
                float ps = 0.f;
#pragma unroll
                for (int ct = 0; ct < 4; ct++) {
                    float p = exp2f((sc[f][ct][rr] - mrow[f][rr]) * LOG2E);
                    sc[f][ct][rr] = p;
                    ps += p;
                }
                ps += __shfl_xor(ps, 1);
                ps += __shfl_xor(ps, 2);
                ps += __shfl_xor(ps, 4);
                ps += __shfl_xor(ps, 8);
                lrow[f][rr] = lrow[f][rr] * alpha[rr] + ps;
            }
#pragma unroll
            for (int c8 = 0; c8 < 8; c8++)
#pragma unroll
                for (int rr = 0; rr < 4; rr++) O[f][c8][rr] *= alpha[rr];

            // Ps reuse safety (frag1 overwrites frag0's slice): drain DS reads.
            asm volatile("s_waitcnt lgkmcnt(0)" ::: "memory");
            __builtin_amdgcn_sched_barrier(0);
#pragma unroll
            for (int ct = 0; ct < 4; ct++)
#pragma unroll
                for (int rr = 0; rr < 4; rr++)
                    Ps[wave][quad * 4 + rr][ct * 16 + l16] = f2bf(sc[f][ct][rr]);
            asm volatile("s_waitcnt lgkmcnt(0)" ::: "memory");
            __builtin_amdgcn_sched_barrier(0);

            // O += P V
            __builtin_amdgcn_s_setprio(1);
#pragma unroll
            for (int ka2 = 0; ka2 < 2; ka2++) {
                short8 pa = *(const short8*)&Ps[wave][l16][ka2 * 32 + quad * 8];
#pragma unroll
                for (int c8 = 0; c8 < 8; c8++) {
                    int r = c8 * 16 + l16;
                    short8 vf = *(const short8*)((const char*)&Vs[cur][0][0] + r * 128 +
                                                 ((((ka2 << 2) + quad) ^ (r & 7)) << 4));
                    O[f][c8] = __builtin_amdgcn_mfma_f32_16x16x32_bf16(pa, vf, O[f][c8], 0, 0, 0);
                }
            }
            __builtin_amdgcn_s_setprio(0);
        }
        // drain prefetch (vmcnt) + all reads of cur before restage; one barrier.
        __syncthreads();
    }
#undef STAGE

    // normalize + store bf16
#pragma unroll
    for (int f = 0; f < 2; f++)
#pragma unroll
        for (int rr = 0; rr < 4; rr++) {
            float inv = 1.f / lrow[f][rr];
            int row = qt * 128 + f * 64 + wave * 16 + quad * 4 + rr;
#pragma unroll
            for (int c8 = 0; c8 < 8; c8++) {
                int d = c8 * 16 + l16;
                Omid[((size_t)b * S_ + row) * E_ + h * D_ + d] = f2bf(O[f][c8][rr] * inv);
            }
        }
}

// =================== legacy fallback kernels (previous passing version) ====

__global__ __launch_bounds__(256) void gemm_bt(const void* __restrict__ A,
                                               const float* __restrict__ Bw,
                                               void* __restrict__ dst,
                                               int aBf16, int dstMode) {
    __shared__ __align__(16) unsigned short As[64][40];
    __shared__ __align__(16) unsigned short Bs[64][40];
    int t = threadIdx.x;
    int wave = t >> 6, lane = t & 63;
    int quad = lane >> 4, l16 = lane & 15;
    floatx4 acc[4];
#pragma unroll
    for (int i = 0; i < 4; i++) acc[i] = (floatx4)(0.f);

    int r = t >> 2, kc = (t & 3) * 8;
    int ra = blockIdx.x * 64 + r;
    int rb = blockIdx.y * 64 + r;

    for (int k0 = 0; k0 < E_; k0 += 32) {
        if (aBf16) {
            const unsigned short* Ab = (const unsigned short*)A + (size_t)ra * E_ + kc + k0;
            *(uint4*)&As[r][kc] = *(const uint4*)Ab;
        } else {
            const float* Af = (const float*)A + (size_t)ra * E_ + kc + k0;
            float4 f0 = *(const float4*)Af;
            float4 f1 = *(const float4*)(Af + 4);
            unsigned short u[8] = {f2bf(f0.x), f2bf(f0.y), f2bf(f0.z), f2bf(f0.w),
                                   f2bf(f1.x), f2bf(f1.y), f2bf(f1.z), f2bf(f1.w)};
            *(uint4*)&As[r][kc] = *(uint4*)u;
        }
        {
            const float* Bf = Bw + (size_t)rb * E_ + kc + k0;
            float4 g0 = *(const float4*)Bf;
            float4 g1 = *(const float4*)(Bf + 4);
            unsigned short u[8] = {f2bf(g0.x), f2bf(g0.y), f2bf(g0.z), f2bf(g0.w),
                                   f2bf(g1.x), f2bf(g1.y), f2bf(g1.z), f2bf(g1.w)};
            *(uint4*)&Bs[r][kc] = *(uint4*)u;
        }
        __syncthreads();
        short8 a = *(const short8*)&As[wave * 16 + l16][quad * 8];
#pragma unroll
        for (int ct = 0; ct < 4; ct++) {
            short8 bfr = *(const short8*)&Bs[ct * 16 + l16][quad * 8];
            acc[ct] = __builtin_amdgcn_mfma_f32_16x16x32_bf16(a, bfr, acc[ct], 0, 0, 0);
        }
        __syncthreads();
    }
#pragma unroll
    for (int ct = 0; ct < 4; ct++) {
#pragma unroll
        for (int rr = 0; rr < 4; rr++) {
            int m = blockIdx.x * 64 + wave * 16 + quad * 4 + rr;
            int n = blockIdx.y * 64 + ct * 16 + l16;
            float val = acc[ct][rr];
            if (dstMode == 0) {
                ((float*)dst)[(size_t)m * E_ + n] = val;
            } else if (dstMode == 1) {
                int b = m >> 11, s = m & 2047, h = n >> 7, d = n & 127;
                ((float*)dst)[(((size_t)(b * H_ + h)) * S_ + s) * D_ + d] = val;
            } else {
                ((unsigned short*)dst)[(size_t)m * E_ + n] = f2bf(val);
            }
        }
    }
}

__global__ __launch_bounds__(256) void attn_fwd(const unsigned short* __restrict__ Qf,
                                                const float* __restrict__ Kb0,
                                                const float* __restrict__ Vb0,
                                                const float* __restrict__ cosT,
                                                const float* __restrict__ sinT,
                                                unsigned short* __restrict__ Omid,
                                                int qtile0) {
    __shared__ __align__(16) unsigned short Ks[64][136];
    __shared__ __align__(16) unsigned short Vt[128][72];
    __shared__ __align__(16) unsigned short Ps[4][16][72];

    int t = threadIdx.x;
    int wave = t >> 6, lane = t & 63;
    int quad = lane >> 4, l16 = lane & 15;
    int qtile = qtile0 + blockIdx.x, h = blockIdx.y;
    const float* Kb = Kb0 + (size_t)h * S_ * D_;
    const float* Vb = Vb0 + (size_t)h * S_ * D_;

    int sq = qtile * 64 + wave * 16 + l16;
    short8 qf[4];
#pragma unroll
    for (int ks = 0; ks < 4; ks++) {
        int d0 = ks * 32 + quad * 8;
        union { uint4 u4; unsigned short u[8]; } un;
        un.u4 = *(const uint4*)&Qf[(size_t)sq * E_ + h * D_ + d0];
#pragma unroll
        for (int i = 0; i < 4; i++) {
            int j = (d0 >> 1) + i;
            float c = cosT[sq * 64 + j], s = sinT[sq * 64 + j];
            float x1 = bf2f(un.u[2 * i]), x2 = bf2f(un.u[2 * i + 1]);
            un.u[2 * i] = f2bf(x1 * c - x2 * s);
            un.u[2 * i + 1] = f2bf(x1 * s + x2 * c);
        }
        qf[ks] = *(short8*)un.u;
    }

    floatx4 O[8];
#pragma unroll
    for (int i = 0; i < 8; i++) O[i] = (floatx4)(0.f);
    float mrow[4], lrow[4];
#pragma unroll
    for (int r = 0; r < 4; r++) { mrow[r] = NEG_S; lrow[r] = 0.f; }

    const float scale = 0.08838834764831845f;

    for (int kt = 0; kt <= qtile; kt++) {
        __syncthreads();
        int r = t >> 2;
#pragma unroll
        for (int it = 0; it < 4; it++) {
            int d0 = (t & 3) * 8 + it * 32;
            int sk = kt * 64 + r;
            float4 ka = *(const float4*)&Kb[(size_t)sk * D_ + d0];
            float4 kb2 = *(const float4*)&Kb[(size_t)sk * D_ + d0 + 4];
            float xs[8] = {ka.x, ka.y, ka.z, ka.w, kb2.x, kb2.y, kb2.z, kb2.w};
            unsigned short u[8];
#pragma unroll
            for (int i = 0; i < 4; i++) {
                int j = (d0 >> 1) + i;
                float c = cosT[sk * 64 + j], s = sinT[sk * 64 + j];
                float x1 = xs[2 * i], x2 = xs[2 * i + 1];
                u[2 * i]     = f2bf(x1 * c - x2 * s);
                u[2 * i + 1] = f2bf(x1 * s + x2 * c);
            }
            *(uint4*)&Ks[r][d0] = *(uint4*)u;
            float4 va = *(const float4*)&Vb[(size_t)sk * D_ + d0];
            float4 vb2 = *(const float4*)&Vb[(size_t)sk * D_ + d0 + 4];
            float vs[8] = {va.x, va.y, va.z, va.w, vb2.x, vb2.y, vb2.z, vb2.w};
#pragma unroll
            for (int i = 0; i < 8; i++) Vt[d0 + i][r] = f2bf(vs[i]);
        }
        __syncthreads();

        floatx4 sc[4];
#pragma unroll
        for (int ct = 0; ct < 4; ct++) sc[ct] = (floatx4)(0.f);
#pragma unroll
        for (int ks = 0; ks < 4; ks++) {
#pragma unroll
            for (int ct = 0; ct < 4; ct++) {
                short8 kf = *(const short8*)&Ks[ct * 16 + l16][ks * 32 + quad * 8];
                sc[ct] = __builtin_amdgcn_mfma_f32_16x16x32_bf16(qf[ks], kf, sc[ct], 0, 0, 0);
            }
        }
        int rowbase = qtile * 64 + wave * 16 + quad * 4;
#pragma unroll
        for (int ct = 0; ct < 4; ct++) {
            int col = kt * 64 + ct * 16 + l16;
#pragma unroll
            for (int rr = 0; rr < 4; rr++) {
                float x = sc[ct][rr] * scale;
                sc[ct][rr] = (col > rowbase + rr) ? NEG_S : x;
            }
        }
        float alpha[4];
#pragma unroll
        for (int rr = 0; rr < 4; rr++) {
            float mx = fmaxf(fmaxf(sc[0][rr], sc[1][rr]), fmaxf(sc[2][rr], sc[3][rr]));
            mx = fmaxf(mx, __shfl_xor(mx, 1));
            mx = fmaxf(mx, __shfl_xor(mx, 2));
            mx = fmaxf(mx, __shfl_xor(mx, 4));
            mx = fmaxf(mx, __shfl_xor(mx, 8));
            float mnew = fmaxf(mrow[rr], mx);
            alpha[rr] = exp2f((mrow[rr] - mnew) * LOG2E);
            mrow[rr] = mnew;
        }
#pragma unroll
        for (int rr = 0; rr < 4; rr++) {
            float ps = 0.f;
#pragma unroll
            for (int ct = 0; ct < 4; ct++) {
                float p = exp2f((sc[ct][rr] - mrow[rr]) * LOG2E);
                sc[ct][rr] = p;
                ps += p;
            }
            ps += __shfl_xor(ps, 1);
            ps += __shfl_xor(ps, 2);
            ps += __shfl_xor(ps, 4);
            ps += __shfl_xor(ps, 8);
            lrow[rr] = lrow[rr] * alpha[rr] + ps;
        }
#pragma unroll
        for (int c8 = 0; c8 < 8; c8++)
#pragma unroll
            for (int rr = 0; rr < 4; rr++) O[c8][rr] *= alpha[rr];

#pragma unroll
        for (int ct = 0; ct < 4; ct++)
#pragma unroll
            for (int rr = 0; rr < 4; rr++)
                Ps[wave][quad * 4 + rr][ct * 16 + l16] = f2bf(sc[ct][rr]);
        __syncthreads();

#pragma unroll
        for (int ka2 = 0; ka2 < 2; ka2++) {
            short8 pa = *(const short8*)&Ps[wave][l16][ka2 * 32 + quad * 8];
#pragma unroll
            for (int c8 = 0; c8 < 8; c8++) {
                short8 vf = *(const short8*)&Vt[c8 * 16 + l16][ka2 * 32 + quad * 8];
                O[c8] = __builtin_amdgcn_mfma_f32_16x16x32_bf16(pa, vf, O[c8], 0, 0, 0);
            }
        }
    }

#pragma unroll
    for (int rr = 0; rr < 4; rr++) {
        float inv = 1.f / lrow[rr];
        int lrw = blockIdx.x * 64 + wave * 16 + quad * 4 + rr;
#pragma unroll
        for (int c8 = 0; c8 < 8; c8++) {
            int d = c8 * 16 + l16;
            Omid[(size_t)lrw * E_ + h * D_ + d] = f2bf(O[c8][rr] * inv);
        }
    }
}

extern "C" void kernel_launch(void* const* d_in, const int* in_sizes, int n_in,
                              void* d_out, int out_size, void* d_ws, size_t ws_size,
                              hipStream_t stream) {
    const float* x  = (const float*)d_in[0];
    const float* Wq = (const float*)d_in[1];
    const float* Wk = (const float*)d_in[2];
    const float* Wv = (const float*)d_in[3];
    const float* Wo = (const float*)d_in[4];

    float* out_attn = (float*)d_out;                              // (B,S,E) fp32
    float* out_k = out_attn + (size_t)B_ * H_ * S_ * D_;          // (B,H,S,D) fp32 pre-rope
    float* out_v = out_k + (size_t)B_ * H_ * S_ * D_;             // (B,H,S,D) fp32

    char* ws = (char*)d_ws;
    float* cosT = (float*)ws;
    float* sinT = cosT + S_ * (D_ / 2);
    size_t tab_bytes = 2u * S_ * (D_ / 2) * sizeof(float);        // 1 MB

    size_t krBytes  = (size_t)B_ * H_ * S_ * D_ * 2;              // 16.8 MB
    size_t wbBytes  = (size_t)E_ * E_ * 2;                        // 8.4 MB
    size_t midBytes = (size_t)B_ * S_ * E_ * 2;                   // 16.8 MB
    size_t needFast = tab_bytes + 2 * krBytes + wbBytes + midBytes; // ~59.8 MB

    hipLaunchKernelGGL(rope_tab, dim3(512), dim3(256), 0, stream, cosT, sinT);

    if (ws_size >= needFast) {
        // ---------------- fast path ----------------
        unsigned short* Kr  = (unsigned short*)(ws + tab_bytes);
        unsigned short* Vt  = Kr + (size_t)B_ * H_ * S_ * D_;
        unsigned short* Wb  = Vt + (size_t)B_ * H_ * S_ * D_;
        unsigned short* mid = Wb + (size_t)E_ * E_;
        unsigned short* xb    = (unsigned short*)out_attn;                       // [0,16.8M)
        unsigned short* q_tmp = (unsigned short*)(out_attn + (size_t)S_ * E_);   // [16.8,33.5M)

        hipLaunchKernelGGL(cvt_bf16, dim3(4096), dim3(256), 0, stream, x, xb, 1048576);

        hipLaunchKernelGGL(cvt_bf16, dim3(2048), dim3(256), 0, stream, Wq, Wb, 524288);
        hipLaunchKernelGGL(gemm128, dim3(32, 16), dim3(256), 0, stream, xb, Wb, (void*)q_tmp, 3);

        hipLaunchKernelGGL(cvt_bf16, dim3(2048), dim3(256), 0, stream, Wk, Wb, 524288);
        hipLaunchKernelGGL(gemm128, dim3(32, 16), dim3(256), 0, stream, xb, Wb, (void*)out_k, 1);
        hipLaunchKernelGGL(prep_k, dim3(4096), dim3(256), 0, stream, out_k, Kr, cosT, sinT);

        hipLaunchKernelGGL(cvt_bf16, dim3(2048), dim3(256), 0, stream, Wv, Wb, 524288);
        hipLaunchKernelGGL(gemm128, dim3(32, 16), dim3(256), 0, stream, xb, Wb, (void*)out_v, 1);
        hipLaunchKernelGGL(prep_v, dim3(32, 32), dim3(256), 0, stream, out_v, Vt);

        hipLaunchKernelGGL(cvt_bf16, dim3(2048), dim3(256), 0, stream, Wo, Wb, 524288);

        hipLaunchKernelGGL(attn_fast2, dim3(512), dim3(256), 0, stream,
                           q_tmp, Kr, Vt, cosT, sinT, mid);
        hipLaunchKernelGGL(gemm128, dim3(32, 16), dim3(256), 0, stream, mid, Wb,
                           (void*)out_attn, 0);
    } else {
        // ---------------- legacy fallback (previous passing version) -------
        unsigned short* q_tmp = (unsigned short*)(out_attn + (size_t)S_ * E_);
        unsigned short* mid = (unsigned short*)(ws + tab_bytes);
        size_t avail = ws_size > tab_bytes ? ws_size - tab_bytes : 0;
        int R = 64;
        for (int r = 2048; r >= 64; r >>= 1) {
            if ((size_t)r * E_ * 2 <= avail) { R = r; break; }
        }

        dim3 gg(64, 32);
        hipLaunchKernelGGL(gemm_bt, gg, dim3(256), 0, stream, (const void*)x, Wq, (void*)q_tmp, 0, 3);
        hipLaunchKernelGGL(gemm_bt, gg, dim3(256), 0, stream, (const void*)x, Wk, (void*)out_k, 0, 1);
        hipLaunchKernelGGL(gemm_bt, gg, dim3(256), 0, stream, (const void*)x, Wv, (void*)out_v, 0, 1);

        const size_t bhsd = (size_t)H_ * S_ * D_;
        for (int b = 0; b < B_; b++) {
            const unsigned short* qb = q_tmp + (size_t)b * S_ * E_;
            for (int c = 0; c < S_ / 64; c += R / 64) {
                hipLaunchKernelGGL(attn_fwd, dim3(R / 64, H_), dim3(256), 0, stream,
                                   qb, out_k + b * bhsd, out_v + b * bhsd,
                                   cosT, sinT, mid, c);
                hipLaunchKernelGGL(gemm_bt, dim3(R / 64, 32), dim3(256), 0, stream,
                                   (const void*)mid, Wo,
                                   (void*)(out_attn + ((size_t)b * S_ + c * 64) * E_), 1, 0);
            }
        }
    }
}

// Round 4
// 592.874 us; speedup vs baseline: 1.0507x; 1.0507x over previous
//
#include <hip/hip_runtime.h>

typedef __attribute__((ext_vector_type(8))) short short8;
typedef __attribute__((ext_vector_type(4))) float floatx4;

#define B_ 2
#define S_ 2048
#define E_ 2048
#define H_ 16
#define D_ 128

#define NEG_S  (-3.0e4f)
#define LOG2E  1.4426950408889634f

__device__ inline float bf2f(unsigned short u) {
    union { unsigned int i; float f; } v; v.i = ((unsigned int)u) << 16; return v.f;
}
__device__ inline unsigned short f2bf(float f) {
    union { float f; unsigned int i; } v; v.f = f;
    unsigned int r = v.i + 0x7FFFu + ((v.i >> 16) & 1u);
    return (unsigned short)(r >> 16);
}

// async global->LDS, 16B per lane. LDS dest is wave-uniform base + lane*16.
__device__ inline void gload_lds16(const void* g, void* l) {
    __builtin_amdgcn_global_load_lds((__attribute__((address_space(1))) void*)(void*)g,
                                     (__attribute__((address_space(3))) void*)l, 16, 0, 0);
}

// Precompute RoPE cos/sin tables: [S][D/2] fp32. 1 MB total.
__global__ void rope_tab(float* __restrict__ cosT, float* __restrict__ sinT) {
    int idx = blockIdx.x * 256 + threadIdx.x;   // 2048*64 entries
    int s = idx >> 6, j = idx & 63;
    float inv = exp2f(-(float)(2 * j) * (13.287712379549449f / 128.0f));
    float ang = (float)s * inv;
    cosT[idx] = cosf(ang);
    sinT[idx] = sinf(ang);
}

// fp32 -> bf16, 8 elems/thread, exact-sized grids.
__global__ __launch_bounds__(256) void cvt_bf16(const float* __restrict__ in,
                                                unsigned short* __restrict__ out, int n8) {
    int i = blockIdx.x * 256 + threadIdx.x;
    if (i >= n8) return;
    float4 f0 = *(const float4*)(in + (size_t)i * 8);
    float4 f1 = *(const float4*)(in + (size_t)i * 8 + 4);
    unsigned short u[8] = {f2bf(f0.x), f2bf(f0.y), f2bf(f0.z), f2bf(f0.w),
                           f2bf(f1.x), f2bf(f1.y), f2bf(f1.z), f2bf(f1.w)};
    *(uint4*)(out + (size_t)i * 8) = *(uint4*)u;
}

// out_k fp32 [B][H][S][D] -> Kr bf16 same layout, RoPE applied once.
__global__ __launch_bounds__(256) void prep_k(const float* __restrict__ K,
                                              unsigned short* __restrict__ Kr,
                                              const float* __restrict__ cosT,
                                              const float* __restrict__ sinT) {
    int idx = blockIdx.x * 256 + threadIdx.x;   // B*H*S*16 = 1,048,576
    int g = idx & 15;
    int s = (idx >> 4) & (S_ - 1);
    const float* src = K + (size_t)idx * 8;
    float4 f0 = *(const float4*)src;
    float4 f1 = *(const float4*)(src + 4);
    float xs[8] = {f0.x, f0.y, f0.z, f0.w, f1.x, f1.y, f1.z, f1.w};
    unsigned short u[8];
    int jb = g * 4;
#pragma unroll
    for (int i = 0; i < 4; i++) {
        float c = cosT[s * 64 + jb + i], sn = sinT[s * 64 + jb + i];
        float x1 = xs[2 * i], x2 = xs[2 * i + 1];
        u[2 * i]     = f2bf(x1 * c - x2 * sn);
        u[2 * i + 1] = f2bf(x1 * sn + x2 * c);
    }
    *(uint4*)(Kr + (size_t)idx * 8) = *(uint4*)u;
}

// out_v fp32 [B][H][S][D] -> Vt bf16 [B][H][D][S] (transposed via LDS).
__global__ __launch_bounds__(256) void prep_v(const float* __restrict__ V,
                                              unsigned short* __restrict__ Vt) {
    __shared__ unsigned short Ls[64][130];
    int bh = blockIdx.y;
    int s0 = blockIdx.x * 64;
    int t = threadIdx.x;
    const float* src = V + ((size_t)bh * S_ + s0) * D_;
#pragma unroll
    for (int it = 0; it < 4; it++) {
        int r = it * 16 + (t >> 4), d0 = (t & 15) * 8;
        float4 f0 = *(const float4*)&src[(size_t)r * D_ + d0];
        float4 f1 = *(const float4*)&src[(size_t)r * D_ + d0 + 4];
        unsigned short u[8] = {f2bf(f0.x), f2bf(f0.y), f2bf(f0.z), f2bf(f0.w),
                               f2bf(f1.x), f2bf(f1.y), f2bf(f1.z), f2bf(f1.w)};
#pragma unroll
        for (int i = 0; i < 8; i++) Ls[r][d0 + i] = u[i];
    }
    __syncthreads();
    unsigned short* dst = Vt + (size_t)bh * D_ * S_;
#pragma unroll
    for (int it = 0; it < 4; it++) {
        int d = it * 32 + (t >> 3), ss = (t & 7) * 8;
        unsigned short u[8];
#pragma unroll
        for (int i = 0; i < 8; i++) u[i] = Ls[ss + i][d];
        *(uint4*)&dst[(size_t)d * S_ + s0 + ss] = *(uint4*)u;
    }
}

// ---- m97-style 128x128-tile bf16 GEMM: C = A @ W^T (unchanged, verified).
__global__ __launch_bounds__(256) void gemm128(const unsigned short* __restrict__ A,
                                               const unsigned short* __restrict__ Bw,
                                               void* __restrict__ dst, int dstMode) {
    __shared__ __align__(16) unsigned short As[128][32];
    __shared__ __align__(16) unsigned short Bs[128][32];
    int t = threadIdx.x;
    int wave = t >> 6, lane = t & 63;
    int quad = lane >> 4, l16 = lane & 15;
    int wr = wave >> 1, wc = wave & 1;

    floatx4 acc[4][4];
#pragma unroll
    for (int m = 0; m < 4; m++)
#pragma unroll
        for (int n = 0; n < 4; n++) acc[m][n] = (floatx4)(0.f);

    int srow = lane >> 2;
    int sg = lane & 3;
    const size_t aRow0 = (size_t)blockIdx.x * 128;
    const size_t bRow0 = (size_t)blockIdx.y * 128;

    for (int k0 = 0; k0 < E_; k0 += 32) {
#pragma unroll
        for (int i = 0; i < 2; i++) {
            int lr = wave * 32 + i * 16 + srow;
            int gg = sg ^ ((lr >> 1) & 3);
            gload_lds16(A + (aRow0 + lr) * E_ + k0 + gg * 8, &As[wave * 32 + i * 16][0]);
            gload_lds16(Bw + (bRow0 + lr) * E_ + k0 + gg * 8, &Bs[wave * 32 + i * 16][0]);
        }
        __syncthreads();
        short8 af[4], bfr[4];
#pragma unroll
        for (int m = 0; m < 4; m++) {
            int r = wr * 64 + m * 16 + l16;
            af[m] = *(const short8*)((const char*)As + r * 64 + ((quad ^ ((r >> 1) & 3)) << 4));
        }
#pragma unroll
        for (int n = 0; n < 4; n++) {
            int r = wc * 64 + n * 16 + l16;
            bfr[n] = *(const short8*)((const char*)Bs + r * 64 + ((quad ^ ((r >> 1) & 3)) << 4));
        }
#pragma unroll
        for (int m = 0; m < 4; m++)
#pragma unroll
            for (int n = 0; n < 4; n++)
                acc[m][n] = __builtin_amdgcn_mfma_f32_16x16x32_bf16(af[m], bfr[n], acc[m][n], 0, 0, 0);
        __syncthreads();
    }
#pragma unroll
    for (int m = 0; m < 4; m++)
#pragma unroll
        for (int n = 0; n < 4; n++)
#pragma unroll
            for (int rr = 0; rr < 4; rr++) {
                int mg = (int)aRow0 + wr * 64 + m * 16 + quad * 4 + rr;
                int ng = (int)bRow0 + wc * 64 + n * 16 + l16;
                float val = acc[m][n][rr];
                if (dstMode == 0) {
                    ((float*)dst)[(size_t)mg * E_ + ng] = val;
                } else if (dstMode == 1) {
                    int b = mg >> 11, s = mg & 2047, h = ng >> 7, d = ng & 127;
                    ((float*)dst)[(((size_t)(b * H_ + h)) * S_ + s) * D_ + d] = val;
                } else {
                    ((unsigned short*)dst)[(size_t)mg * E_ + ng] = f2bf(val);
                }
            }
}

// ---- Flash attention v4: r1 structure (QBLK=64, single-buffered staging,
// measured 177us) + occupancy push: LDS 41984->40960 (Ps [16][72]->[16][64]
// with 16B-granule XOR swizzle) so 4 blocks/CU fit exactly in 160KiB, and
// __launch_bounds__(256,4) (VGPR cap 128; r1 compiled at 88 so safe).
// Grid (512, B): per-XCD 2 heads (L2-resident K/V), qtile descending (LPT).
__global__ __launch_bounds__(256, 4) void attn_fast4(const unsigned short* __restrict__ Qf,
                                                     const unsigned short* __restrict__ Kr,
                                                     const unsigned short* __restrict__ Vt,
                                                     const float* __restrict__ cosT,
                                                     const float* __restrict__ sinT,
                                                     unsigned short* __restrict__ Omid) {
    __shared__ __align__(16) unsigned short Ks[64][128];
    __shared__ __align__(16) unsigned short Vs[128][64];
    __shared__ __align__(16) unsigned short Ps[4][16][64];   // XOR-swizzled granules

    int t = threadIdx.x;
    int wave = t >> 6, lane = t & 63;
    int quad = lane >> 4, l16 = lane & 15;
    int orig = blockIdx.x;                      // 0..511
    int L = (orig & 7) * 64 + (orig >> 3);      // XCD-chunked bijection
    int h = L >> 5;
    int qtile = 31 - (L & 31);                  // heavy tiles first
    int b = blockIdx.y;

    const unsigned short* Qb = Qf + (size_t)b * S_ * E_;
    const unsigned short* Kh = Kr + ((size_t)(b * H_ + h)) * S_ * D_;
    const unsigned short* Vh = Vt + ((size_t)(b * H_ + h)) * D_ * S_;

    // Q fragments (A-operand: row=l16, k=quad*8+j), roped in-register.
    int sq = qtile * 64 + wave * 16 + l16;
    short8 qf[4];
#pragma unroll
    for (int ks = 0; ks < 4; ks++) {
        int d0 = ks * 32 + quad * 8;
        union { uint4 u4; unsigned short u[8]; } un;
        un.u4 = *(const uint4*)&Qb[(size_t)sq * E_ + h * D_ + d0];
#pragma unroll
        for (int i = 0; i < 4; i++) {
            int j = (d0 >> 1) + i;
            float c = cosT[sq * 64 + j], s = sinT[sq * 64 + j];
            float x1 = bf2f(un.u[2 * i]), x2 = bf2f(un.u[2 * i + 1]);
            un.u[2 * i] = f2bf(x1 * c - x2 * s);
            un.u[2 * i + 1] = f2bf(x1 * s + x2 * c);
        }
        qf[ks] = *(short8*)un.u;
    }

    floatx4 O[8];
#pragma unroll
    for (int i = 0; i < 8; i++) O[i] = (floatx4)(0.f);
    float mrow[4], lrow[4];
#pragma unroll
    for (int r = 0; r < 4; r++) { mrow[r] = NEG_S; lrow[r] = 0.f; }

    const float scale = 0.08838834764831845f; // 1/sqrt(128)
    char* pbase = (char*)&Ps[wave][0][0];

    for (int kt = 0; kt <= qtile; kt++) {
        // Stage K tile (64x128 bf16) and V slice (128x64 bf16), linear LDS,
        // inverse-swizzled global source (granule ^= row&7).
#pragma unroll
        for (int i = 0; i < 4; i++) {
            int r = wave * 16 + i * 4 + (lane >> 4);          // K local row 0..63
            int g = (lane & 15) ^ (r & 7);
            gload_lds16(&Kh[(size_t)(kt * 64 + r) * D_ + g * 8], &Ks[wave * 16 + i * 4][0]);
        }
#pragma unroll
        for (int i = 0; i < 4; i++) {
            int r = wave * 32 + i * 8 + (lane >> 3);          // V d-row 0..127
            int g = (lane & 7) ^ (r & 7);
            gload_lds16(&Vh[(size_t)r * S_ + kt * 64 + g * 8], &Vs[wave * 32 + i * 8][0]);
        }
        __syncthreads();

        // S = Q K^T (per wave: 16 rows x 64 cols)
        floatx4 sc[4];
#pragma unroll
        for (int ct = 0; ct < 4; ct++) sc[ct] = (floatx4)(0.f);
        __builtin_amdgcn_s_setprio(1);
#pragma unroll
        for (int ks = 0; ks < 4; ks++) {
#pragma unroll
            for (int ct = 0; ct < 4; ct++) {
                int r = ct * 16 + l16;
                short8 kf = *(const short8*)((const char*)Ks + r * 256 +
                                             ((((ks << 2) + quad) ^ (r & 7)) << 4));
                sc[ct] = __builtin_amdgcn_mfma_f32_16x16x32_bf16(qf[ks], kf, sc[ct], 0, 0, 0);
            }
        }
        __builtin_amdgcn_s_setprio(0);
        // scale + causal mask
        int rowbase = qtile * 64 + wave * 16 + quad * 4;
#pragma unroll
        for (int ct = 0; ct < 4; ct++) {
            int col = kt * 64 + ct * 16 + l16;
#pragma unroll
            for (int rr = 0; rr < 4; rr++) {
                float x = sc[ct][rr] * scale;
                sc[ct][rr] = (col > rowbase + rr) ? NEG_S : x;
            }
        }
        // online softmax (row reductions across 16 lanes of each quad-row)
        float alpha[4];
#pragma unroll
        for (int rr = 0; rr < 4; rr++) {
            float mx = fmaxf(fmaxf(sc[0][rr], sc[1][rr]), fmaxf(sc[2][rr], sc[3][rr]));
            mx = fmaxf(mx, __shfl_xor(mx, 1));
            mx = fmaxf(mx, __shfl_xor(mx, 2));
            mx = fmaxf(mx, __shfl_xor(mx, 4));
            mx = fmaxf(mx, __shfl_xor(mx, 8));
            float mnew = fmaxf(mrow[rr], mx);
            alpha[rr] = exp2f((mrow[rr] - mnew) * LOG2E);
            mrow[rr] = mnew;
        }
#pragma unroll
        for (int rr = 0; rr < 4; rr++) {
            float ps = 0.f;
#pragma unroll
            for (int ct = 0; ct < 4; ct++) {
                float p = exp2f((sc[ct][rr] - mrow[rr]) * LOG2E);
                sc[ct][rr] = p;
                ps += p;
            }
            ps += __shfl_xor(ps, 1);
            ps += __shfl_xor(ps, 2);
            ps += __shfl_xor(ps, 4);
            ps += __shfl_xor(ps, 8);
            lrow[rr] = lrow[rr] * alpha[rr] + ps;
        }
#pragma unroll
        for (int c8 = 0; c8 < 8; c8++)
#pragma unroll
            for (int rr = 0; rr < 4; rr++) O[c8][rr] *= alpha[rr];

        // P: C-layout -> per-wave LDS slice (XOR-swizzled 16B granules)
#pragma unroll
        for (int ct = 0; ct < 4; ct++)
#pragma unroll
            for (int rr = 0; rr < 4; rr++) {
                int row = quad * 4 + rr;
                int byteoff = (row << 7) + (((ct * 16 + l16) << 1) ^ ((row & 7) << 4));
                *(unsigned short*)(pbase + byteoff) = f2bf(sc[ct][rr]);
            }
        asm volatile("s_waitcnt lgkmcnt(0)" ::: "memory");
        __builtin_amdgcn_sched_barrier(0);

        // O += P V
        __builtin_amdgcn_s_setprio(1);
#pragma unroll
        for (int ka2 = 0; ka2 < 2; ka2++) {
            int pboff = (l16 << 7) + ((ka2 * 64 + quad * 16) ^ ((l16 & 7) << 4));
            short8 pa = *(const short8*)(pbase + pboff);
#pragma unroll
            for (int c8 = 0; c8 < 8; c8++) {
                int r = c8 * 16 + l16;
                short8 vf = *(const short8*)((const char*)Vs + r * 128 +
                                             ((((ka2 << 2) + quad) ^ (r & 7)) << 4));
                O[c8] = __builtin_amdgcn_mfma_f32_16x16x32_bf16(pa, vf, O[c8], 0, 0, 0);
            }
        }
        __builtin_amdgcn_s_setprio(0);
        asm volatile("s_waitcnt lgkmcnt(0)" ::: "memory");
        __builtin_amdgcn_sched_barrier(0);
        __syncthreads();   // all Ks/Vs/Ps reads done before restage
    }

    // normalize + store bf16 (full-batch layout)
#pragma unroll
    for (int rr = 0; rr < 4; rr++) {
        float inv = 1.f / lrow[rr];
        int row = qtile * 64 + wave * 16 + quad * 4 + rr;
#pragma unroll
        for (int c8 = 0; c8 < 8; c8++) {
            int d = c8 * 16 + l16;
            Omid[((size_t)b * S_ + row) * E_ + h * D_ + d] = f2bf(O[c8][rr] * inv);
        }
    }
}

// =================== legacy fallback kernels (previous passing version) ====

__global__ __launch_bounds__(256) void gemm_bt(const void* __restrict__ A,
                                               const float* __restrict__ Bw,
                                               void* __restrict__ dst,
                                               int aBf16, int dstMode) {
    __shared__ __align__(16) unsigned short As[64][40];
    __shared__ __align__(16) unsigned short Bs[64][40];
    int t = threadIdx.x;
    int wave = t >> 6, lane = t & 63;
    int quad = lane >> 4, l16 = lane & 15;
    floatx4 acc[4];
#pragma unroll
    for (int i = 0; i < 4; i++) acc[i] = (floatx4)(0.f);

    int r = t >> 2, kc = (t & 3) * 8;
    int ra = blockIdx.x * 64 + r;
    int rb = blockIdx.y * 64 + r;

    for (int k0 = 0; k0 < E_; k0 += 32) {
        if (aBf16) {
            const unsigned short* Ab = (const unsigned short*)A + (size_t)ra * E_ + kc + k0;
            *(uint4*)&As[r][kc] = *(const uint4*)Ab;
        } else {
            const float* Af = (const float*)A + (size_t)ra * E_ + kc + k0;
            float4 f0 = *(const float4*)Af;
            float4 f1 = *(const float4*)(Af + 4);
            unsigned short u[8] = {f2bf(f0.x), f2bf(f0.y), f2bf(f0.z), f2bf(f0.w),
                                   f2bf(f1.x), f2bf(f1.y), f2bf(f1.z), f2bf(f1.w)};
            *(uint4*)&As[r][kc] = *(uint4*)u;
        }
        {
            const float* Bf = Bw + (size_t)rb * E_ + kc + k0;
            float4 g0 = *(const float4*)Bf;
            float4 g1 = *(const float4*)(Bf + 4);
            unsigned short u[8] = {f2bf(g0.x), f2bf(g0.y), f2bf(g0.z), f2bf(g0.w),
                                   f2bf(g1.x), f2bf(g1.y), f2bf(g1.z), f2bf(g1.w)};
            *(uint4*)&Bs[r][kc] = *(uint4*)u;
        }
        __syncthreads();
        short8 a = *(const short8*)&As[wave * 16 + l16][quad * 8];
#pragma unroll
        for (int ct = 0; ct < 4; ct++) {
            short8 bfr = *(const short8*)&Bs[ct * 16 + l16][quad * 8];
            acc[ct] = __builtin_amdgcn_mfma_f32_16x16x32_bf16(a, bfr, acc[ct], 0, 0, 0);
        }
        __syncthreads();
    }
#pragma unroll
    for (int ct = 0; ct < 4; ct++) {
#pragma unroll
        for (int rr = 0; rr < 4; rr++) {
            int m = blockIdx.x * 64 + wave * 16 + quad * 4 + rr;
            int n = blockIdx.y * 64 + ct * 16 + l16;
            float val = acc[ct][rr];
            if (dstMode == 0) {
                ((float*)dst)[(size_t)m * E_ + n] = val;
            } else if (dstMode == 1) {
                int b = m >> 11, s = m & 2047, h = n >> 7, d = n & 127;
                ((float*)dst)[(((size_t)(b * H_ + h)) * S_ + s) * D_ + d] = val;
            } else {
                ((unsigned short*)dst)[(size_t)m * E_ + n] = f2bf(val);
            }
        }
    }
}

__global__ __launch_bounds__(256) void attn_fwd(const unsigned short* __restrict__ Qf,
                                                const float* __restrict__ Kb0,
                                                const float* __restrict__ Vb0,
                                                const float* __restrict__ cosT,
                                                const float* __restrict__ sinT,
                                                unsigned short* __restrict__ Omid,
                                                int qtile0) {
    __shared__ __align__(16) unsigned short Ks[64][136];
    __shared__ __align__(16) unsigned short Vt[128][72];
    __shared__ __align__(16) unsigned short Ps[4][16][72];

    int t = threadIdx.x;
    int wave = t >> 6, lane = t & 63;
    int quad = lane >> 4, l16 = lane & 15;
    int qtile = qtile0 + blockIdx.x, h = blockIdx.y;
    const float* Kb = Kb0 + (size_t)h * S_ * D_;
    const float* Vb = Vb0 + (size_t)h * S_ * D_;

    int sq = qtile * 64 + wave * 16 + l16;
    short8 qf[4];
#pragma unroll
    for (int ks = 0; ks < 4; ks++) {
        int d0 = ks * 32 + quad * 8;
        union { uint4 u4; unsigned short u[8]; } un;
        un.u4 = *(const uint4*)&Qf[(size_t)sq * E_ + h * D_ + d0];
#pragma unroll
        for (int i = 0; i < 4; i++) {
            int j = (d0 >> 1) + i;
            float c = cosT[sq * 64 + j], s = sinT[sq * 64 + j];
            float x1 = bf2f(un.u[2 * i]), x2 = bf2f(un.u[2 * i + 1]);
            un.u[2 * i] = f2bf(x1 * c - x2 * s);
            un.u[2 * i + 1] = f2bf(x1 * s + x2 * c);
        }
        qf[ks] = *(short8*)un.u;
    }

    floatx4 O[8];
#pragma unroll
    for (int i = 0; i < 8; i++) O[i] = (floatx4)(0.f);
    float mrow[4], lrow[4];
#pragma unroll
    for (int r = 0; r < 4; r++) { mrow[r] = NEG_S; lrow[r] = 0.f; }

    const float scale = 0.08838834764831845f;

    for (int kt = 0; kt <= qtile; kt++) {
        __syncthreads();
        int r = t >> 2;
#pragma unroll
        for (int it = 0; it < 4; it++) {
            int d0 = (t & 3) * 8 + it * 32;
            int sk = kt * 64 + r;
            float4 ka = *(const float4*)&Kb[(size_t)sk * D_ + d0];
            float4 kb2 = *(const float4*)&Kb[(size_t)sk * D_ + d0 + 4];
            float xs[8] = {ka.x, ka.y, ka.z, ka.w, kb2.x, kb2.y, kb2.z, kb2.w};
            unsigned short u[8];
#pragma unroll
            for (int i = 0; i < 4; i++) {
                int j = (d0 >> 1) + i;
                float c = cosT[sk * 64 + j], s = sinT[sk * 64 + j];
                float x1 = xs[2 * i], x2 = xs[2 * i + 1];
                u[2 * i]     = f2bf(x1 * c - x2 * s);
                u[2 * i + 1] = f2bf(x1 * s + x2 * c);
            }
            *(uint4*)&Ks[r][d0] = *(uint4*)u;
            float4 va = *(const float4*)&Vb[(size_t)sk * D_ + d0];
            float4 vb2 = *(const float4*)&Vb[(size_t)sk * D_ + d0 + 4];
            float vs[8] = {va.x, va.y, va.z, va.w, vb2.x, vb2.y, vb2.z, vb2.w};
#pragma unroll
            for (int i = 0; i < 8; i++) Vt[d0 + i][r] = f2bf(vs[i]);
        }
        __syncthreads();

        floatx4 sc[4];
#pragma unroll
        for (int ct = 0; ct < 4; ct++) sc[ct] = (floatx4)(0.f);
#pragma unroll
        for (int ks = 0; ks < 4; ks++) {
#pragma unroll
            for (int ct = 0; ct < 4; ct++) {
                short8 kf = *(const short8*)&Ks[ct * 16 + l16][ks * 32 + quad * 8];
                sc[ct] = __builtin_amdgcn_mfma_f32_16x16x32_bf16(qf[ks], kf, sc[ct], 0, 0, 0);
            }
        }
        int rowbase = qtile * 64 + wave * 16 + quad * 4;
#pragma unroll
        for (int ct = 0; ct < 4; ct++) {
            int col = kt * 64 + ct * 16 + l16;
#pragma unroll
            for (int rr = 0; rr < 4; rr++) {
                float x = sc[ct][rr] * scale;
                sc[ct][rr] = (col > rowbase + rr) ? NEG_S : x;
            }
        }
        float alpha[4];
#pragma unroll
        for (int rr = 0; rr < 4; rr++) {
            float mx = fmaxf(fmaxf(sc[0][rr], sc[1][rr]), fmaxf(sc[2][rr], sc[3][rr]));
            mx = fmaxf(mx, __shfl_xor(mx, 1));
            mx = fmaxf(mx, __shfl_xor(mx, 2));
            mx = fmaxf(mx, __shfl_xor(mx, 4));
            mx = fmaxf(mx, __shfl_xor(mx, 8));
            float mnew = fmaxf(mrow[rr], mx);
            alpha[rr] = exp2f((mrow[rr] - mnew) * LOG2E);
            mrow[rr] = mnew;
        }
#pragma unroll
        for (int rr = 0; rr < 4; rr++) {
            float ps = 0.f;
#pragma unroll
            for (int ct = 0; ct < 4; ct++) {
                float p = exp2f((sc[ct][rr] - mrow[rr]) * LOG2E);
                sc[ct][rr] = p;
                ps += p;
            }
            ps += __shfl_xor(ps, 1);
            ps += __shfl_xor(ps, 2);
            ps += __shfl_xor(ps, 4);
            ps += __shfl_xor(ps, 8);
            lrow[rr] = lrow[rr] * alpha[rr] + ps;
        }
#pragma unroll
        for (int c8 = 0; c8 < 8; c8++)
#pragma unroll
            for (int rr = 0; rr < 4; rr++) O[c8][rr] *= alpha[rr];

#pragma unroll
        for (int ct = 0; ct < 4; ct++)
#pragma unroll
            for (int rr = 0; rr < 4; rr++)
                Ps[wave][quad * 4 + rr][ct * 16 + l16] = f2bf(sc[ct][rr]);
        __syncthreads();

#pragma unroll
        for (int ka2 = 0; ka2 < 2; ka2++) {
            short8 pa = *(const short8*)&Ps[wave][l16][ka2 * 32 + quad * 8];
#pragma unroll
            for (int c8 = 0; c8 < 8; c8++) {
                short8 vf = *(const short8*)&Vt[c8 * 16 + l16][ka2 * 32 + quad * 8];
                O[c8] = __builtin_amdgcn_mfma_f32_16x16x32_bf16(pa, vf, O[c8], 0, 0, 0);
            }
        }
    }

#pragma unroll
    for (int rr = 0; rr < 4; rr++) {
        float inv = 1.f / lrow[rr];
        int lrw = blockIdx.x * 64 + wave * 16 + quad * 4 + rr;
#pragma unroll
        for (int c8 = 0; c8 < 8; c8++) {
            int d = c8 * 16 + l16;
            Omid[(size_t)lrw * E_ + h * D_ + d] = f2bf(O[c8][rr] * inv);
        }
    }
}

extern "C" void kernel_launch(void* const* d_in, const int* in_sizes, int n_in,
                              void* d_out, int out_size, void* d_ws, size_t ws_size,
                              hipStream_t stream) {
    const float* x  = (const float*)d_in[0];
    const float* Wq = (const float*)d_in[1];
    const float* Wk = (const float*)d_in[2];
    const float* Wv = (const float*)d_in[3];
    const float* Wo = (const float*)d_in[4];

    float* out_attn = (float*)d_out;                              // (B,S,E) fp32
    float* out_k = out_attn + (size_t)B_ * H_ * S_ * D_;          // (B,H,S,D) fp32 pre-rope
    float* out_v = out_k + (size_t)B_ * H_ * S_ * D_;             // (B,H,S,D) fp32

    char* ws = (char*)d_ws;
    float* cosT = (float*)ws;
    float* sinT = cosT + S_ * (D_ / 2);
    size_t tab_bytes = 2u * S_ * (D_ / 2) * sizeof(float);        // 1 MB

    size_t krBytes  = (size_t)B_ * H_ * S_ * D_ * 2;              // 16.8 MB
    size_t wbBytes  = (size_t)E_ * E_ * 2;                        // 8.4 MB
    size_t midBytes = (size_t)B_ * S_ * E_ * 2;                   // 16.8 MB
    size_t needFast = tab_bytes + 2 * krBytes + wbBytes + midBytes; // ~59.8 MB

    hipLaunchKernelGGL(rope_tab, dim3(512), dim3(256), 0, stream, cosT, sinT);

    if (ws_size >= needFast) {
        // ---------------- fast path ----------------
        unsigned short* Kr  = (unsigned short*)(ws + tab_bytes);
        unsigned short* Vt  = Kr + (size_t)B_ * H_ * S_ * D_;
        unsigned short* Wb  = Vt + (size_t)B_ * H_ * S_ * D_;
        unsigned short* mid = Wb + (size_t)E_ * E_;
        unsigned short* xb    = (unsigned short*)out_attn;                       // [0,16.8M)
        unsigned short* q_tmp = (unsigned short*)(out_attn + (size_t)S_ * E_);   // [16.8,33.5M)

        hipLaunchKernelGGL(cvt_bf16, dim3(4096), dim3(256), 0, stream, x, xb, 1048576);

        hipLaunchKernelGGL(cvt_bf16, dim3(2048), dim3(256), 0, stream, Wq, Wb, 524288);
        hipLaunchKernelGGL(gemm128, dim3(32, 16), dim3(256), 0, stream, xb, Wb, (void*)q_tmp, 3);

        hipLaunchKernelGGL(cvt_bf16, dim3(2048), dim3(256), 0, stream, Wk, Wb, 524288);
        hipLaunchKernelGGL(gemm128, dim3(32, 16), dim3(256), 0, stream, xb, Wb, (void*)out_k, 1);
        hipLaunchKernelGGL(prep_k, dim3(4096), dim3(256), 0, stream, out_k, Kr, cosT, sinT);

        hipLaunchKernelGGL(cvt_bf16, dim3(2048), dim3(256), 0, stream, Wv, Wb, 524288);
        hipLaunchKernelGGL(gemm128, dim3(32, 16), dim3(256), 0, stream, xb, Wb, (void*)out_v, 1);
        hipLaunchKernelGGL(prep_v, dim3(32, 32), dim3(256), 0, stream, out_v, Vt);

        hipLaunchKernelGGL(cvt_bf16, dim3(2048), dim3(256), 0, stream, Wo, Wb, 524288);

        hipLaunchKernelGGL(attn_fast4, dim3(512, B_), dim3(256), 0, stream,
                           q_tmp, Kr, Vt, cosT, sinT, mid);
        hipLaunchKernelGGL(gemm128, dim3(32, 16), dim3(256), 0, stream, mid, Wb,
                           (void*)out_attn, 0);
    } else {
        // ---------------- legacy fallback (previous passing version) -------
        unsigned short* q_tmp = (unsigned short*)(out_attn + (size_t)S_ * E_);
        unsigned short* mid = (unsigned short*)(ws + tab_bytes);
        size_t avail = ws_size > tab_bytes ? ws_size - tab_bytes : 0;
        int R = 64;
        for (int r = 2048; r >= 64; r >>= 1) {
            if ((size_t)r * E_ * 2 <= avail) { R = r; break; }
        }

        dim3 gg(64, 32);
        hipLaunchKernelGGL(gemm_bt, gg, dim3(256), 0, stream, (const void*)x, Wq, (void*)q_tmp, 0, 3);
        hipLaunchKernelGGL(gemm_bt, gg, dim3(256), 0, stream, (const void*)x, Wk, (void*)out_k, 0, 1);
        hipLaunchKernelGGL(gemm_bt, gg, dim3(256), 0, stream, (const void*)x, Wv, (void*)out_v, 0, 1);

        const size_t bhsd = (size_t)H_ * S_ * D_;
        for (int b = 0; b < B_; b++) {
            const unsigned short* qb = q_tmp + (size_t)b * S_ * E_;
            for (int c = 0; c < S_ / 64; c += R / 64) {
                hipLaunchKernelGGL(attn_fwd, dim3(R / 64, H_), dim3(256), 0, stream,
                                   qb, out_k + b * bhsd, out_v + b * bhsd,
                                   cosT, sinT, mid, c);
                hipLaunchKernelGGL(gemm_bt, dim3(R / 64, 32), dim3(256), 0, stream,
                                   (const void*)mid, Wo,
                                   (void*)(out_attn + ((size_t)b * S_ + c * 64) * E_), 1, 0);
            }
        }
    }
}

// Round 5
// 550.746 us; speedup vs baseline: 1.1310x; 1.0765x over previous
//
#include <hip/hip_runtime.h>

typedef __attribute__((ext_vector_type(8))) short short8;
typedef __attribute__((ext_vector_type(4))) float floatx4;

#define B_ 2
#define S_ 2048
#define E_ 2048
#define H_ 16
#define D_ 128

#define NEG_S  (-3.0e4f)
#define LOG2E  1.4426950408889634f

__device__ inline float bf2f(unsigned short u) {
    union { unsigned int i; float f; } v; v.i = ((unsigned int)u) << 16; return v.f;
}
__device__ inline unsigned short f2bf(float f) {
    union { float f; unsigned int i; } v; v.f = f;
    unsigned int r = v.i + 0x7FFFu + ((v.i >> 16) & 1u);
    return (unsigned short)(r >> 16);
}

// async global->LDS, 16B per lane. LDS dest is wave-uniform base + lane*16.
__device__ inline void gload_lds16(const void* g, void* l) {
    __builtin_amdgcn_global_load_lds((__attribute__((address_space(1))) void*)(void*)g,
                                     (__attribute__((address_space(3))) void*)l, 16, 0, 0);
}

// Precompute RoPE cos/sin tables: [S][D/2] fp32. 1 MB total.
__global__ void rope_tab(float* __restrict__ cosT, float* __restrict__ sinT) {
    int idx = blockIdx.x * 256 + threadIdx.x;   // 2048*64 entries
    int s = idx >> 6, j = idx & 63;
    float inv = exp2f(-(float)(2 * j) * (13.287712379549449f / 128.0f));
    float ang = (float)s * inv;
    cosT[idx] = cosf(ang);
    sinT[idx] = sinf(ang);
}

// fp32 -> bf16, 8 elems/thread, exact-sized grids.
__global__ __launch_bounds__(256) void cvt_bf16(const float* __restrict__ in,
                                                unsigned short* __restrict__ out, int n8) {
    int i = blockIdx.x * 256 + threadIdx.x;
    if (i >= n8) return;
    float4 f0 = *(const float4*)(in + (size_t)i * 8);
    float4 f1 = *(const float4*)(in + (size_t)i * 8 + 4);
    unsigned short u[8] = {f2bf(f0.x), f2bf(f0.y), f2bf(f0.z), f2bf(f0.w),
                           f2bf(f1.x), f2bf(f1.y), f2bf(f1.z), f2bf(f1.w)};
    *(uint4*)(out + (size_t)i * 8) = *(uint4*)u;
}

// out_k fp32 [B][H][S][D] -> Kr bf16 same layout, RoPE applied once.
__global__ __launch_bounds__(256) void prep_k(const float* __restrict__ K,
                                              unsigned short* __restrict__ Kr,
                                              const float* __restrict__ cosT,
                                              const float* __restrict__ sinT) {
    int idx = blockIdx.x * 256 + threadIdx.x;   // B*H*S*16 = 1,048,576
    int g = idx & 15;
    int s = (idx >> 4) & (S_ - 1);
    const float* src = K + (size_t)idx * 8;
    float4 f0 = *(const float4*)src;
    float4 f1 = *(const float4*)(src + 4);
    float xs[8] = {f0.x, f0.y, f0.z, f0.w, f1.x, f1.y, f1.z, f1.w};
    unsigned short u[8];
    int jb = g * 4;
#pragma unroll
    for (int i = 0; i < 4; i++) {
        float c = cosT[s * 64 + jb + i], sn = sinT[s * 64 + jb + i];
        float x1 = xs[2 * i], x2 = xs[2 * i + 1];
        u[2 * i]     = f2bf(x1 * c - x2 * sn);
        u[2 * i + 1] = f2bf(x1 * sn + x2 * c);
    }
    *(uint4*)(Kr + (size_t)idx * 8) = *(uint4*)u;
}

// out_v fp32 [B][H][S][D] -> Vt bf16 [B][H][D][S] (transposed via LDS).
__global__ __launch_bounds__(256) void prep_v(const float* __restrict__ V,
                                              unsigned short* __restrict__ Vt) {
    __shared__ unsigned short Ls[64][130];
    int bh = blockIdx.y;
    int s0 = blockIdx.x * 64;
    int t = threadIdx.x;
    const float* src = V + ((size_t)bh * S_ + s0) * D_;
#pragma unroll
    for (int it = 0; it < 4; it++) {
        int r = it * 16 + (t >> 4), d0 = (t & 15) * 8;
        float4 f0 = *(const float4*)&src[(size_t)r * D_ + d0];
        float4 f1 = *(const float4*)&src[(size_t)r * D_ + d0 + 4];
        unsigned short u[8] = {f2bf(f0.x), f2bf(f0.y), f2bf(f0.z), f2bf(f0.w),
                               f2bf(f1.x), f2bf(f1.y), f2bf(f1.z), f2bf(f1.w)};
#pragma unroll
        for (int i = 0; i < 8; i++) Ls[r][d0 + i] = u[i];
    }
    __syncthreads();
    unsigned short* dst = Vt + (size_t)bh * D_ * S_;
#pragma unroll
    for (int it = 0; it < 4; it++) {
        int d = it * 32 + (t >> 3), ss = (t & 7) * 8;
        unsigned short u[8];
#pragma unroll
        for (int i = 0; i < 8; i++) u[i] = Ls[ss + i][d];
        *(uint4*)&dst[(size_t)d * S_ + s0 + ss] = *(uint4*)u;
    }
}

// ---- m97-style 128x128-tile bf16 GEMM: C = A @ W^T (unchanged, verified).
__global__ __launch_bounds__(256) void gemm128(const unsigned short* __restrict__ A,
                                               const unsigned short* __restrict__ Bw,
                                               void* __restrict__ dst, int dstMode) {
    __shared__ __align__(16) unsigned short As[128][32];
    __shared__ __align__(16) unsigned short Bs[128][32];
    int t = threadIdx.x;
    int wave = t >> 6, lane = t & 63;
    int quad = lane >> 4, l16 = lane & 15;
    int wr = wave >> 1, wc = wave & 1;

    floatx4 acc[4][4];
#pragma unroll
    for (int m = 0; m < 4; m++)
#pragma unroll
        for (int n = 0; n < 4; n++) acc[m][n] = (floatx4)(0.f);

    int srow = lane >> 2;
    int sg = lane & 3;
    const size_t aRow0 = (size_t)blockIdx.x * 128;
    const size_t bRow0 = (size_t)blockIdx.y * 128;

    for (int k0 = 0; k0 < E_; k0 += 32) {
#pragma unroll
        for (int i = 0; i < 2; i++) {
            int lr = wave * 32 + i * 16 + srow;
            int gg = sg ^ ((lr >> 1) & 3);
            gload_lds16(A + (aRow0 + lr) * E_ + k0 + gg * 8, &As[wave * 32 + i * 16][0]);
            gload_lds16(Bw + (bRow0 + lr) * E_ + k0 + gg * 8, &Bs[wave * 32 + i * 16][0]);
        }
        __syncthreads();
        short8 af[4], bfr[4];
#pragma unroll
        for (int m = 0; m < 4; m++) {
            int r = wr * 64 + m * 16 + l16;
            af[m] = *(const short8*)((const char*)As + r * 64 + ((quad ^ ((r >> 1) & 3)) << 4));
        }
#pragma unroll
        for (int n = 0; n < 4; n++) {
            int r = wc * 64 + n * 16 + l16;
            bfr[n] = *(const short8*)((const char*)Bs + r * 64 + ((quad ^ ((r >> 1) & 3)) << 4));
        }
#pragma unroll
        for (int m = 0; m < 4; m++)
#pragma unroll
            for (int n = 0; n < 4; n++)
                acc[m][n] = __builtin_amdgcn_mfma_f32_16x16x32_bf16(af[m], bfr[n], acc[m][n], 0, 0, 0);
        __syncthreads();
    }
#pragma unroll
    for (int m = 0; m < 4; m++)
#pragma unroll
        for (int n = 0; n < 4; n++)
#pragma unroll
            for (int rr = 0; rr < 4; rr++) {
                int mg = (int)aRow0 + wr * 64 + m * 16 + quad * 4 + rr;
                int ng = (int)bRow0 + wc * 64 + n * 16 + l16;
                float val = acc[m][n][rr];
                if (dstMode == 0) {
                    ((float*)dst)[(size_t)mg * E_ + ng] = val;
                } else if (dstMode == 1) {
                    int b = mg >> 11, s = mg & 2047, h = ng >> 7, d = ng & 127;
                    ((float*)dst)[(((size_t)(b * H_ + h)) * S_ + s) * D_ + d] = val;
                } else {
                    ((unsigned short*)dst)[(size_t)mg * E_ + ng] = f2bf(val);
                }
            }
}

// ---- Flash attention v5 = v4 WITHOUT the min-waves launch bound.
// LDS 40960 B (Ks 16K + Vs 16K + Ps 8K swizzled) -> 4 blocks/CU from the LDS
// limit alone. VGPR floats (~90-110 <= 128 -> 4 waves/SIMD), NO spills.
// r4 lesson: (256,4) over-shrank VGPR to 64 and spilled (WRITE_SIZE 2.4x).
__global__ __launch_bounds__(256) void attn_fast5(const unsigned short* __restrict__ Qf,
                                                  const unsigned short* __restrict__ Kr,
                                                  const unsigned short* __restrict__ Vt,
                                                  const float* __restrict__ cosT,
                                                  const float* __restrict__ sinT,
                                                  unsigned short* __restrict__ Omid) {
    __shared__ __align__(16) unsigned short Ks[64][128];
    __shared__ __align__(16) unsigned short Vs[128][64];
    __shared__ __align__(16) unsigned short Ps[4][16][64];   // XOR-swizzled granules

    int t = threadIdx.x;
    int wave = t >> 6, lane = t & 63;
    int quad = lane >> 4, l16 = lane & 15;
    int orig = blockIdx.x;                      // 0..511
    int L = (orig & 7) * 64 + (orig >> 3);      // XCD-chunked bijection
    int h = L >> 5;
    int qtile = 31 - (L & 31);                  // heavy tiles first
    int b = blockIdx.y;

    const unsigned short* Qb = Qf + (size_t)b * S_ * E_;
    const unsigned short* Kh = Kr + ((size_t)(b * H_ + h)) * S_ * D_;
    const unsigned short* Vh = Vt + ((size_t)(b * H_ + h)) * D_ * S_;

    // Q fragments (A-operand: row=l16, k=quad*8+j), roped in-register.
    int sq = qtile * 64 + wave * 16 + l16;
    short8 qf[4];
#pragma unroll
    for (int ks = 0; ks < 4; ks++) {
        int d0 = ks * 32 + quad * 8;
        union { uint4 u4; unsigned short u[8]; } un;
        un.u4 = *(const uint4*)&Qb[(size_t)sq * E_ + h * D_ + d0];
#pragma unroll
        for (int i = 0; i < 4; i++) {
            int j = (d0 >> 1) + i;
            float c = cosT[sq * 64 + j], s = sinT[sq * 64 + j];
            float x1 = bf2f(un.u[2 * i]), x2 = bf2f(un.u[2 * i + 1]);
            un.u[2 * i] = f2bf(x1 * c - x2 * s);
            un.u[2 * i + 1] = f2bf(x1 * s + x2 * c);
        }
        qf[ks] = *(short8*)un.u;
    }

    floatx4 O[8];
#pragma unroll
    for (int i = 0; i < 8; i++) O[i] = (floatx4)(0.f);
    float mrow[4], lrow[4];
#pragma unroll
    for (int r = 0; r < 4; r++) { mrow[r] = NEG_S; lrow[r] = 0.f; }

    const float scale = 0.08838834764831845f; // 1/sqrt(128)
    char* pbase = (char*)&Ps[wave][0][0];

    for (int kt = 0; kt <= qtile; kt++) {
        // Stage K tile (64x128 bf16) and V slice (128x64 bf16), linear LDS,
        // inverse-swizzled global source (granule ^= row&7).
#pragma unroll
        for (int i = 0; i < 4; i++) {
            int r = wave * 16 + i * 4 + (lane >> 4);          // K local row 0..63
            int g = (lane & 15) ^ (r & 7);
            gload_lds16(&Kh[(size_t)(kt * 64 + r) * D_ + g * 8], &Ks[wave * 16 + i * 4][0]);
        }
#pragma unroll
        for (int i = 0; i < 4; i++) {
            int r = wave * 32 + i * 8 + (lane >> 3);          // V d-row 0..127
            int g = (lane & 7) ^ (r & 7);
            gload_lds16(&Vh[(size_t)r * S_ + kt * 64 + g * 8], &Vs[wave * 32 + i * 8][0]);
        }
        __syncthreads();

        // S = Q K^T (per wave: 16 rows x 64 cols)
        floatx4 sc[4];
#pragma unroll
        for (int ct = 0; ct < 4; ct++) sc[ct] = (floatx4)(0.f);
        __builtin_amdgcn_s_setprio(1);
#pragma unroll
        for (int ks = 0; ks < 4; ks++) {
#pragma unroll
            for (int ct = 0; ct < 4; ct++) {
                int r = ct * 16 + l16;
                short8 kf = *(const short8*)((const char*)Ks + r * 256 +
                                             ((((ks << 2) + quad) ^ (r & 7)) << 4));
                sc[ct] = __builtin_amdgcn_mfma_f32_16x16x32_bf16(qf[ks], kf, sc[ct], 0, 0, 0);
            }
        }
        __builtin_amdgcn_s_setprio(0);
        // scale + causal mask
        int rowbase = qtile * 64 + wave * 16 + quad * 4;
#pragma unroll
        for (int ct = 0; ct < 4; ct++) {
            int col = kt * 64 + ct * 16 + l16;
#pragma unroll
            for (int rr = 0; rr < 4; rr++) {
                float x = sc[ct][rr] * scale;
                sc[ct][rr] = (col > rowbase + rr) ? NEG_S : x;
            }
        }
        // online softmax (row reductions across 16 lanes of each quad-row)
        float alpha[4];
#pragma unroll
        for (int rr = 0; rr < 4; rr++) {
            float mx = fmaxf(fmaxf(sc[0][rr], sc[1][rr]), fmaxf(sc[2][rr], sc[3][rr]));
            mx = fmaxf(mx, __shfl_xor(mx, 1));
            mx = fmaxf(mx, __shfl_xor(mx, 2));
            mx = fmaxf(mx, __shfl_xor(mx, 4));
            mx = fmaxf(mx, __shfl_xor(mx, 8));
            float mnew = fmaxf(mrow[rr], mx);
            alpha[rr] = exp2f((mrow[rr] - mnew) * LOG2E);
            mrow[rr] = mnew;
        }
#pragma unroll
        for (int rr = 0; rr < 4; rr++) {
            float ps = 0.f;
#pragma unroll
            for (int ct = 0; ct < 4; ct++) {
                float p = exp2f((sc[ct][rr] - mrow[rr]) * LOG2E);
                sc[ct][rr] = p;
                ps += p;
            }
            ps += __shfl_xor(ps, 1);
            ps += __shfl_xor(ps, 2);
            ps += __shfl_xor(ps, 4);
            ps += __shfl_xor(ps, 8);
            lrow[rr] = lrow[rr] * alpha[rr] + ps;
        }
#pragma unroll
        for (int c8 = 0; c8 < 8; c8++)
#pragma unroll
            for (int rr = 0; rr < 4; rr++) O[c8][rr] *= alpha[rr];

        // P: C-layout -> per-wave LDS slice (XOR-swizzled 16B granules)
#pragma unroll
        for (int ct = 0; ct < 4; ct++)
#pragma unroll
            for (int rr = 0; rr < 4; rr++) {
                int row = quad * 4 + rr;
                int byteoff = (row << 7) + (((ct * 16 + l16) << 1) ^ ((row & 7) << 4));
                *(unsigned short*)(pbase + byteoff) = f2bf(sc[ct][rr]);
            }
        asm volatile("s_waitcnt lgkmcnt(0)" ::: "memory");
        __builtin_amdgcn_sched_barrier(0);

        // O += P V
        __builtin_amdgcn_s_setprio(1);
#pragma unroll
        for (int ka2 = 0; ka2 < 2; ka2++) {
            int pboff = (l16 << 7) + ((ka2 * 64 + quad * 16) ^ ((l16 & 7) << 4));
            short8 pa = *(const short8*)(pbase + pboff);
#pragma unroll
            for (int c8 = 0; c8 < 8; c8++) {
                int r = c8 * 16 + l16;
                short8 vf = *(const short8*)((const char*)Vs + r * 128 +
                                             ((((ka2 << 2) + quad) ^ (r & 7)) << 4));
                O[c8] = __builtin_amdgcn_mfma_f32_16x16x32_bf16(pa, vf, O[c8], 0, 0, 0);
            }
        }
        __builtin_amdgcn_s_setprio(0);
        asm volatile("s_waitcnt lgkmcnt(0)" ::: "memory");
        __builtin_amdgcn_sched_barrier(0);
        __syncthreads();   // all Ks/Vs/Ps reads done before restage
    }

    // normalize + store bf16 (full-batch layout)
#pragma unroll
    for (int rr = 0; rr < 4; rr++) {
        float inv = 1.f / lrow[rr];
        int row = qtile * 64 + wave * 16 + quad * 4 + rr;
#pragma unroll
        for (int c8 = 0; c8 < 8; c8++) {
            int d = c8 * 16 + l16;
            Omid[((size_t)b * S_ + row) * E_ + h * D_ + d] = f2bf(O[c8][rr] * inv);
        }
    }
}

// =================== legacy fallback kernels (previous passing version) ====

__global__ __launch_bounds__(256) void gemm_bt(const void* __restrict__ A,
                                               const float* __restrict__ Bw,
                                               void* __restrict__ dst,
                                               int aBf16, int dstMode) {
    __shared__ __align__(16) unsigned short As[64][40];
    __shared__ __align__(16) unsigned short Bs[64][40];
    int t = threadIdx.x;
    int wave = t >> 6, lane = t & 63;
    int quad = lane >> 4, l16 = lane & 15;
    floatx4 acc[4];
#pragma unroll
    for (int i = 0; i < 4; i++) acc[i] = (floatx4)(0.f);

    int r = t >> 2, kc = (t & 3) * 8;
    int ra = blockIdx.x * 64 + r;
    int rb = blockIdx.y * 64 + r;

    for (int k0 = 0; k0 < E_; k0 += 32) {
        if (aBf16) {
            const unsigned short* Ab = (const unsigned short*)A + (size_t)ra * E_ + kc + k0;
            *(uint4*)&As[r][kc] = *(const uint4*)Ab;
        } else {
            const float* Af = (const float*)A + (size_t)ra * E_ + kc + k0;
            float4 f0 = *(const float4*)Af;
            float4 f1 = *(const float4*)(Af + 4);
            unsigned short u[8] = {f2bf(f0.x), f2bf(f0.y), f2bf(f0.z), f2bf(f0.w),
                                   f2bf(f1.x), f2bf(f1.y), f2bf(f1.z), f2bf(f1.w)};
            *(uint4*)&As[r][kc] = *(uint4*)u;
        }
        {
            const float* Bf = Bw + (size_t)rb * E_ + kc + k0;
            float4 g0 = *(const float4*)Bf;
            float4 g1 = *(const float4*)(Bf + 4);
            unsigned short u[8] = {f2bf(g0.x), f2bf(g0.y), f2bf(g0.z), f2bf(g0.w),
                                   f2bf(g1.x), f2bf(g1.y), f2bf(g1.z), f2bf(g1.w)};
            *(uint4*)&Bs[r][kc] = *(uint4*)u;
        }
        __syncthreads();
        short8 a = *(const short8*)&As[wave * 16 + l16][quad * 8];
#pragma unroll
        for (int ct = 0; ct < 4; ct++) {
            short8 bfr = *(const short8*)&Bs[ct * 16 + l16][quad * 8];
            acc[ct] = __builtin_amdgcn_mfma_f32_16x16x32_bf16(a, bfr, acc[ct], 0, 0, 0);
        }
        __syncthreads();
    }
#pragma unroll
    for (int ct = 0; ct < 4; ct++) {
#pragma unroll
        for (int rr = 0; rr < 4; rr++) {
            int m = blockIdx.x * 64 + wave * 16 + quad * 4 + rr;
            int n = blockIdx.y * 64 + ct * 16 + l16;
            float val = acc[ct][rr];
            if (dstMode == 0) {
                ((float*)dst)[(size_t)m * E_ + n] = val;
            } else if (dstMode == 1) {
                int b = m >> 11, s = m & 2047, h = n >> 7, d = n & 127;
                ((float*)dst)[(((size_t)(b * H_ + h)) * S_ + s) * D_ + d] = val;
            } else {
                ((unsigned short*)dst)[(size_t)m * E_ + n] = f2bf(val);
            }
        }
    }
}

__global__ __launch_bounds__(256) void attn_fwd(const unsigned short* __restrict__ Qf,
                                                const float* __restrict__ Kb0,
                                                const float* __restrict__ Vb0,
                                                const float* __restrict__ cosT,
                                                const float* __restrict__ sinT,
                                                unsigned short* __restrict__ Omid,
                                                int qtile0) {
    __shared__ __align__(16) unsigned short Ks[64][136];
    __shared__ __align__(16) unsigned short Vt[128][72];
    __shared__ __align__(16) unsigned short Ps[4][16][72];

    int t = threadIdx.x;
    int wave = t >> 6, lane = t & 63;
    int quad = lane >> 4, l16 = lane & 15;
    int qtile = qtile0 + blockIdx.x, h = blockIdx.y;
    const float* Kb = Kb0 + (size_t)h * S_ * D_;
    const float* Vb = Vb0 + (size_t)h * S_ * D_;

    int sq = qtile * 64 + wave * 16 + l16;
    short8 qf[4];
#pragma unroll
    for (int ks = 0; ks < 4; ks++) {
        int d0 = ks * 32 + quad * 8;
        union { uint4 u4; unsigned short u[8]; } un;
        un.u4 = *(const uint4*)&Qf[(size_t)sq * E_ + h * D_ + d0];
#pragma unroll
        for (int i = 0; i < 4; i++) {
            int j = (d0 >> 1) + i;
            float c = cosT[sq * 64 + j], s = sinT[sq * 64 + j];
            float x1 = bf2f(un.u[2 * i]), x2 = bf2f(un.u[2 * i + 1]);
            un.u[2 * i] = f2bf(x1 * c - x2 * s);
            un.u[2 * i + 1] = f2bf(x1 * s + x2 * c);
        }
        qf[ks] = *(short8*)un.u;
    }

    floatx4 O[8];
#pragma unroll
    for (int i = 0; i < 8; i++) O[i] = (floatx4)(0.f);
    float mrow[4], lrow[4];
#pragma unroll
    for (int r = 0; r < 4; r++) { mrow[r] = NEG_S; lrow[r] = 0.f; }

    const float scale = 0.08838834764831845f;

    for (int kt = 0; kt <= qtile; kt++) {
        __syncthreads();
        int r = t >> 2;
#pragma unroll
        for (int it = 0; it < 4; it++) {
            int d0 = (t & 3) * 8 + it * 32;
            int sk = kt * 64 + r;
            float4 ka = *(const float4*)&Kb[(size_t)sk * D_ + d0];
            float4 kb2 = *(const float4*)&Kb[(size_t)sk * D_ + d0 + 4];
            float xs[8] = {ka.x, ka.y, ka.z, ka.w, kb2.x, kb2.y, kb2.z, kb2.w};
            unsigned short u[8];
#pragma unroll
            for (int i = 0; i < 4; i++) {
                int j = (d0 >> 1) + i;
                float c = cosT[sk * 64 + j], s = sinT[sk * 64 + j];
                float x1 = xs[2 * i], x2 = xs[2 * i + 1];
                u[2 * i]     = f2bf(x1 * c - x2 * s);
                u[2 * i + 1] = f2bf(x1 * s + x2 * c);
            }
            *(uint4*)&Ks[r][d0] = *(uint4*)u;
            float4 va = *(const float4*)&Vb[(size_t)sk * D_ + d0];
            float4 vb2 = *(const float4*)&Vb[(size_t)sk * D_ + d0 + 4];
            float vs[8] = {va.x, va.y, va.z, va.w, vb2.x, vb2.y, vb2.z, vb2.w};
#pragma unroll
            for (int i = 0; i < 8; i++) Vt[d0 + i][r] = f2bf(vs[i]);
        }
        __syncthreads();

        floatx4 sc[4];
#pragma unroll
        for (int ct = 0; ct < 4; ct++) sc[ct] = (floatx4)(0.f);
#pragma unroll
        for (int ks = 0; ks < 4; ks++) {
#pragma unroll
            for (int ct = 0; ct < 4; ct++) {
                short8 kf = *(const short8*)&Ks[ct * 16 + l16][ks * 32 + quad * 8];
                sc[ct] = __builtin_amdgcn_mfma_f32_16x16x32_bf16(qf[ks], kf, sc[ct], 0, 0, 0);
            }
        }
        int rowbase = qtile * 64 + wave * 16 + quad * 4;
#pragma unroll
        for (int ct = 0; ct < 4; ct++) {
            int col = kt * 64 + ct * 16 + l16;
#pragma unroll
            for (int rr = 0; rr < 4; rr++) {
                float x = sc[ct][rr] * scale;
                sc[ct][rr] = (col > rowbase + rr) ? NEG_S : x;
            }
        }
        float alpha[4];
#pragma unroll
        for (int rr = 0; rr < 4; rr++) {
            float mx = fmaxf(fmaxf(sc[0][rr], sc[1][rr]), fmaxf(sc[2][rr], sc[3][rr]));
            mx = fmaxf(mx, __shfl_xor(mx, 1));
            mx = fmaxf(mx, __shfl_xor(mx, 2));
            mx = fmaxf(mx, __shfl_xor(mx, 4));
            mx = fmaxf(mx, __shfl_xor(mx, 8));
            float mnew = fmaxf(mrow[rr], mx);
            alpha[rr] = exp2f((mrow[rr] - mnew) * LOG2E);
            mrow[rr] = mnew;
        }
#pragma unroll
        for (int rr = 0; rr < 4; rr++) {
            float ps = 0.f;
#pragma unroll
            for (int ct = 0; ct < 4; ct++) {
                float p = exp2f((sc[ct][rr] - mrow[rr]) * LOG2E);
                sc[ct][rr] = p;
                ps += p;
            }
            ps += __shfl_xor(ps, 1);
            ps += __shfl_xor(ps, 2);
            ps += __shfl_xor(ps, 4);
            ps += __shfl_xor(ps, 8);
            lrow[rr] = lrow[rr] * alpha[rr] + ps;
        }
#pragma unroll
        for (int c8 = 0; c8 < 8; c8++)
#pragma unroll
            for (int rr = 0; rr < 4; rr++) O[c8][rr] *= alpha[rr];

#pragma unroll
        for (int ct = 0; ct < 4; ct++)
#pragma unroll
            for (int rr = 0; rr < 4; rr++)
                Ps[wave][quad * 4 + rr][ct * 16 + l16] = f2bf(sc[ct][rr]);
        __syncthreads();

#pragma unroll
        for (int ka2 = 0; ka2 < 2; ka2++) {
            short8 pa = *(const short8*)&Ps[wave][l16][ka2 * 32 + quad * 8];
#pragma unroll
            for (int c8 = 0; c8 < 8; c8++) {
                short8 vf = *(const short8*)&Vt[c8 * 16 + l16][ka2 * 32 + quad * 8];
                O[c8] = __builtin_amdgcn_mfma_f32_16x16x32_bf16(pa, vf, O[c8], 0, 0, 0);
            }
        }
    }

#pragma unroll
    for (int rr = 0; rr < 4; rr++) {
        float inv = 1.f / lrow[rr];
        int lrw = blockIdx.x * 64 + wave * 16 + quad * 4 + rr;
#pragma unroll
        for (int c8 = 0; c8 < 8; c8++) {
            int d = c8 * 16 + l16;
            Omid[(size_t)lrw * E_ + h * D_ + d] = f2bf(O[c8][rr] * inv);
        }
    }
}

extern "C" void kernel_launch(void* const* d_in, const int* in_sizes, int n_in,
                              void* d_out, int out_size, void* d_ws, size_t ws_size,
                              hipStream_t stream) {
    const float* x  = (const float*)d_in[0];
    const float* Wq = (const float*)d_in[1];
    const float* Wk = (const float*)d_in[2];
    const float* Wv = (const float*)d_in[3];
    const float* Wo = (const float*)d_in[4];

    float* out_attn = (float*)d_out;                              // (B,S,E) fp32
    float* out_k = out_attn + (size_t)B_ * H_ * S_ * D_;          // (B,H,S,D) fp32 pre-rope
    float* out_v = out_k + (size_t)B_ * H_ * S_ * D_;             // (B,H,S,D) fp32

    char* ws = (char*)d_ws;
    float* cosT = (float*)ws;
    float* sinT = cosT + S_ * (D_ / 2);
    size_t tab_bytes = 2u * S_ * (D_ / 2) * sizeof(float);        // 1 MB

    size_t krBytes  = (size_t)B_ * H_ * S_ * D_ * 2;              // 16.8 MB
    size_t wbBytes  = (size_t)E_ * E_ * 2;                        // 8.4 MB
    size_t midBytes = (size_t)B_ * S_ * E_ * 2;                   // 16.8 MB
    size_t needFast = tab_bytes + 2 * krBytes + wbBytes + midBytes; // ~59.8 MB

    hipLaunchKernelGGL(rope_tab, dim3(512), dim3(256), 0, stream, cosT, sinT);

    if (ws_size >= needFast) {
        // ---------------- fast path ----------------
        unsigned short* Kr  = (unsigned short*)(ws + tab_bytes);
        unsigned short* Vt  = Kr + (size_t)B_ * H_ * S_ * D_;
        unsigned short* Wb  = Vt + (size_t)B_ * H_ * S_ * D_;
        unsigned short* mid = Wb + (size_t)E_ * E_;
        unsigned short* xb    = (unsigned short*)out_attn;                       // [0,16.8M)
        unsigned short* q_tmp = (unsigned short*)(out_attn + (size_t)S_ * E_);   // [16.8,33.5M)

        hipLaunchKernelGGL(cvt_bf16, dim3(4096), dim3(256), 0, stream, x, xb, 1048576);

        hipLaunchKernelGGL(cvt_bf16, dim3(2048), dim3(256), 0, stream, Wq, Wb, 524288);
        hipLaunchKernelGGL(gemm128, dim3(32, 16), dim3(256), 0, stream, xb, Wb, (void*)q_tmp, 3);

        hipLaunchKernelGGL(cvt_bf16, dim3(2048), dim3(256), 0, stream, Wk, Wb, 524288);
        hipLaunchKernelGGL(gemm128, dim3(32, 16), dim3(256), 0, stream, xb, Wb, (void*)out_k, 1);
        hipLaunchKernelGGL(prep_k, dim3(4096), dim3(256), 0, stream, out_k, Kr, cosT, sinT);

        hipLaunchKernelGGL(cvt_bf16, dim3(2048), dim3(256), 0, stream, Wv, Wb, 524288);
        hipLaunchKernelGGL(gemm128, dim3(32, 16), dim3(256), 0, stream, xb, Wb, (void*)out_v, 1);
        hipLaunchKernelGGL(prep_v, dim3(32, 32), dim3(256), 0, stream, out_v, Vt);

        hipLaunchKernelGGL(cvt_bf16, dim3(2048), dim3(256), 0, stream, Wo, Wb, 524288);

        hipLaunchKernelGGL(attn_fast5, dim3(512, B_), dim3(256), 0, stream,
                           q_tmp, Kr, Vt, cosT, sinT, mid);
        hipLaunchKernelGGL(gemm128, dim3(32, 16), dim3(256), 0, stream, mid, Wb,
                           (void*)out_attn, 0);
    } else {
        // ---------------- legacy fallback (previous passing version) -------
        unsigned short* q_tmp = (unsigned short*)(out_attn + (size_t)S_ * E_);
        unsigned short* mid = (unsigned short*)(ws + tab_bytes);
        size_t avail = ws_size > tab_bytes ? ws_size - tab_bytes : 0;
        int R = 64;
        for (int r = 2048; r >= 64; r >>= 1) {
            if ((size_t)r * E_ * 2 <= avail) { R = r; break; }
        }

        dim3 gg(64, 32);
        hipLaunchKernelGGL(gemm_bt, gg, dim3(256), 0, stream, (const void*)x, Wq, (void*)q_tmp, 0, 3);
        hipLaunchKernelGGL(gemm_bt, gg, dim3(256), 0, stream, (const void*)x, Wk, (void*)out_k, 0, 1);
        hipLaunchKernelGGL(gemm_bt, gg, dim3(256), 0, stream, (const void*)x, Wv, (void*)out_v, 0, 1);

        const size_t bhsd = (size_t)H_ * S_ * D_;
        for (int b = 0; b < B_; b++) {
            const unsigned short* qb = q_tmp + (size_t)b * S_ * E_;
            for (int c = 0; c < S_ / 64; c += R / 64) {
                hipLaunchKernelGGL(attn_fwd, dim3(R / 64, H_), dim3(256), 0, stream,
                                   qb, out_k + b * bhsd, out_v + b * bhsd,
                                   cosT, sinT, mid, c);
                hipLaunchKernelGGL(gemm_bt, dim3(R / 64, 32), dim3(256), 0, stream,
                                   (const void*)mid, Wo,
                                   (void*)(out_attn + ((size_t)b * S_ + c * 64) * E_), 1, 0);
            }
        }
    }
}

// Round 6
// 533.977 us; speedup vs baseline: 1.1666x; 1.0314x over previous
//
#include <hip/hip_runtime.h>

typedef __attribute__((ext_vector_type(8))) short short8;
typedef __attribute__((ext_vector_type(4))) float floatx4;

#define B_ 2
#define S_ 2048
#define E_ 2048
#define H_ 16
#define D_ 128

#define NEG_S  (-3.0e4f)
#define LOG2E  1.4426950408889634f

__device__ inline float bf2f(unsigned short u) {
    union { unsigned int i; float f; } v; v.i = ((unsigned int)u) << 16; return v.f;
}
__device__ inline unsigned short f2bf(float f) {
    union { float f; unsigned int i; } v; v.f = f;
    unsigned int r = v.i + 0x7FFFu + ((v.i >> 16) & 1u);
    return (unsigned short)(r >> 16);
}

// async global->LDS, 16B per lane. LDS dest is wave-uniform base + lane*16.
__device__ inline void gload_lds16(const void* g, void* l) {
    __builtin_amdgcn_global_load_lds((__attribute__((address_space(1))) void*)(void*)g,
                                     (__attribute__((address_space(3))) void*)l, 16, 0, 0);
}

// Precompute RoPE cos/sin tables: [S][D/2] fp32. 1 MB total.
__global__ void rope_tab(float* __restrict__ cosT, float* __restrict__ sinT) {
    int idx = blockIdx.x * 256 + threadIdx.x;   // 2048*64 entries
    int s = idx >> 6, j = idx & 63;
    float inv = exp2f(-(float)(2 * j) * (13.287712379549449f / 128.0f));
    float ang = (float)s * inv;
    cosT[idx] = cosf(ang);
    sinT[idx] = sinf(ang);
}

// fp32 -> bf16, 8 elems/thread, exact-sized grids.
__global__ __launch_bounds__(256) void cvt_bf16(const float* __restrict__ in,
                                                unsigned short* __restrict__ out, int n8) {
    int i = blockIdx.x * 256 + threadIdx.x;
    if (i >= n8) return;
    float4 f0 = *(const float4*)(in + (size_t)i * 8);
    float4 f1 = *(const float4*)(in + (size_t)i * 8 + 4);
    unsigned short u[8] = {f2bf(f0.x), f2bf(f0.y), f2bf(f0.z), f2bf(f0.w),
                           f2bf(f1.x), f2bf(f1.y), f2bf(f1.z), f2bf(f1.w)};
    *(uint4*)(out + (size_t)i * 8) = *(uint4*)u;
}

// out_k fp32 [B][H][S][D] -> Kr bf16 same layout, RoPE applied once.
__global__ __launch_bounds__(256) void prep_k(const float* __restrict__ K,
                                              unsigned short* __restrict__ Kr,
                                              const float* __restrict__ cosT,
                                              const float* __restrict__ sinT) {
    int idx = blockIdx.x * 256 + threadIdx.x;   // B*H*S*16 = 1,048,576
    int g = idx & 15;
    int s = (idx >> 4) & (S_ - 1);
    const float* src = K + (size_t)idx * 8;
    float4 f0 = *(const float4*)src;
    float4 f1 = *(const float4*)(src + 4);
    float xs[8] = {f0.x, f0.y, f0.z, f0.w, f1.x, f1.y, f1.z, f1.w};
    unsigned short u[8];
    int jb = g * 4;
#pragma unroll
    for (int i = 0; i < 4; i++) {
        float c = cosT[s * 64 + jb + i], sn = sinT[s * 64 + jb + i];
        float x1 = xs[2 * i], x2 = xs[2 * i + 1];
        u[2 * i]     = f2bf(x1 * c - x2 * sn);
        u[2 * i + 1] = f2bf(x1 * sn + x2 * c);
    }
    *(uint4*)(Kr + (size_t)idx * 8) = *(uint4*)u;
}

// out_v fp32 [B][H][S][D] -> Vt bf16 [B][H][D][S] (transposed via LDS).
__global__ __launch_bounds__(256) void prep_v(const float* __restrict__ V,
                                              unsigned short* __restrict__ Vt) {
    __shared__ unsigned short Ls[64][130];
    int bh = blockIdx.y;
    int s0 = blockIdx.x * 64;
    int t = threadIdx.x;
    const float* src = V + ((size_t)bh * S_ + s0) * D_;
#pragma unroll
    for (int it = 0; it < 4; it++) {
        int r = it * 16 + (t >> 4), d0 = (t & 15) * 8;
        float4 f0 = *(const float4*)&src[(size_t)r * D_ + d0];
        float4 f1 = *(const float4*)&src[(size_t)r * D_ + d0 + 4];
        unsigned short u[8] = {f2bf(f0.x), f2bf(f0.y), f2bf(f0.z), f2bf(f0.w),
                               f2bf(f1.x), f2bf(f1.y), f2bf(f1.z), f2bf(f1.w)};
#pragma unroll
        for (int i = 0; i < 8; i++) Ls[r][d0 + i] = u[i];
    }
    __syncthreads();
    unsigned short* dst = Vt + (size_t)bh * D_ * S_;
#pragma unroll
    for (int it = 0; it < 4; it++) {
        int d = it * 32 + (t >> 3), ss = (t & 7) * 8;
        unsigned short u[8];
#pragma unroll
        for (int i = 0; i < 8; i++) u[i] = Ls[ss + i][d];
        *(uint4*)&dst[(size_t)d * S_ + s0 + ss] = *(uint4*)u;
    }
}

// ---- m97-style 128x128-tile bf16 GEMM: C = A @ W^T (unchanged, verified).
__global__ __launch_bounds__(256) void gemm128(const unsigned short* __restrict__ A,
                                               const unsigned short* __restrict__ Bw,
                                               void* __restrict__ dst, int dstMode) {
    __shared__ __align__(16) unsigned short As[128][32];
    __shared__ __align__(16) unsigned short Bs[128][32];
    int t = threadIdx.x;
    int wave = t >> 6, lane = t & 63;
    int quad = lane >> 4, l16 = lane & 15;
    int wr = wave >> 1, wc = wave & 1;

    floatx4 acc[4][4];
#pragma unroll
    for (int m = 0; m < 4; m++)
#pragma unroll
        for (int n = 0; n < 4; n++) acc[m][n] = (floatx4)(0.f);

    int srow = lane >> 2;
    int sg = lane & 3;
    const size_t aRow0 = (size_t)blockIdx.x * 128;
    const size_t bRow0 = (size_t)blockIdx.y * 128;

    for (int k0 = 0; k0 < E_; k0 += 32) {
#pragma unroll
        for (int i = 0; i < 2; i++) {
            int lr = wave * 32 + i * 16 + srow;
            int gg = sg ^ ((lr >> 1) & 3);
            gload_lds16(A + (aRow0 + lr) * E_ + k0 + gg * 8, &As[wave * 32 + i * 16][0]);
            gload_lds16(Bw + (bRow0 + lr) * E_ + k0 + gg * 8, &Bs[wave * 32 + i * 16][0]);
        }
        __syncthreads();
        short8 af[4], bfr[4];
#pragma unroll
        for (int m = 0; m < 4; m++) {
            int r = wr * 64 + m * 16 + l16;
            af[m] = *(const short8*)((const char*)As + r * 64 + ((quad ^ ((r >> 1) & 3)) << 4));
        }
#pragma unroll
        for (int n = 0; n < 4; n++) {
            int r = wc * 64 + n * 16 + l16;
            bfr[n] = *(const short8*)((const char*)Bs + r * 64 + ((quad ^ ((r >> 1) & 3)) << 4));
        }
#pragma unroll
        for (int m = 0; m < 4; m++)
#pragma unroll
            for (int n = 0; n < 4; n++)
                acc[m][n] = __builtin_amdgcn_mfma_f32_16x16x32_bf16(af[m], bfr[n], acc[m][n], 0, 0, 0);
        __syncthreads();
    }
#pragma unroll
    for (int m = 0; m < 4; m++)
#pragma unroll
        for (int n = 0; n < 4; n++)
#pragma unroll
            for (int rr = 0; rr < 4; rr++) {
                int mg = (int)aRow0 + wr * 64 + m * 16 + quad * 4 + rr;
                int ng = (int)bRow0 + wc * 64 + n * 16 + l16;
                float val = acc[m][n][rr];
                if (dstMode == 0) {
                    ((float*)dst)[(size_t)mg * E_ + ng] = val;
                } else if (dstMode == 1) {
                    int b = mg >> 11, s = mg & 2047, h = ng >> 7, d = ng & 127;
                    ((float*)dst)[(((size_t)(b * H_ + h)) * S_ + s) * D_ + d] = val;
                } else {
                    ((unsigned short*)dst)[(size_t)mg * E_ + ng] = f2bf(val);
                }
            }
}

// ---- Flash attention v6 = v5 + CU-level LPT fix.
// r5 post-mortem: with L=(orig&7)*64+(orig>>3), the 4 blocks co-resident on a
// CU (linear ids c, c+32 within an XCD, x2 batches) all had the SAME qtile ->
// per-CU work ranged 4..128 iters (anti-balanced). Fix: flip qtile on head
// parity so same-CU pair gets (q, 31-q) -> every CU totals 66 iters.
__global__ __launch_bounds__(256) void attn_fast6(const unsigned short* __restrict__ Qf,
                                                  const unsigned short* __restrict__ Kr,
                                                  const unsigned short* __restrict__ Vt,
                                                  const float* __restrict__ cosT,
                                                  const float* __restrict__ sinT,
                                                  unsigned short* __restrict__ Omid) {
    __shared__ __align__(16) unsigned short Ks[64][128];
    __shared__ __align__(16) unsigned short Vs[128][64];
    __shared__ __align__(16) unsigned short Ps[4][16][64];   // XOR-swizzled granules

    int t = threadIdx.x;
    int wave = t >> 6, lane = t & 63;
    int quad = lane >> 4, l16 = lane & 15;
    int orig = blockIdx.x;                      // 0..511
    int L = (orig & 7) * 64 + (orig >> 3);      // XCD-chunked bijection
    int h = L >> 5;                             // 2 heads per XCD (L2-resident K/V)
    int q5 = L & 31;
    int qtile = (h & 1) ? (31 - q5) : q5;       // CU-level LPT: pair (q, 31-q)
    int b = blockIdx.y;

    const unsigned short* Qb = Qf + (size_t)b * S_ * E_;
    const unsigned short* Kh = Kr + ((size_t)(b * H_ + h)) * S_ * D_;
    const unsigned short* Vh = Vt + ((size_t)(b * H_ + h)) * D_ * S_;

    // Q fragments (A-operand: row=l16, k=quad*8+j), roped in-register.
    int sq = qtile * 64 + wave * 16 + l16;
    short8 qf[4];
#pragma unroll
    for (int ks = 0; ks < 4; ks++) {
        int d0 = ks * 32 + quad * 8;
        union { uint4 u4; unsigned short u[8]; } un;
        un.u4 = *(const uint4*)&Qb[(size_t)sq * E_ + h * D_ + d0];
#pragma unroll
        for (int i = 0; i < 4; i++) {
            int j = (d0 >> 1) + i;
            float c = cosT[sq * 64 + j], s = sinT[sq * 64 + j];
            float x1 = bf2f(un.u[2 * i]), x2 = bf2f(un.u[2 * i + 1]);
            un.u[2 * i] = f2bf(x1 * c - x2 * s);
            un.u[2 * i + 1] = f2bf(x1 * s + x2 * c);
        }
        qf[ks] = *(short8*)un.u;
    }

    floatx4 O[8];
#pragma unroll
    for (int i = 0; i < 8; i++) O[i] = (floatx4)(0.f);
    float mrow[4], lrow[4];
#pragma unroll
    for (int r = 0; r < 4; r++) { mrow[r] = NEG_S; lrow[r] = 0.f; }

    const float scale = 0.08838834764831845f; // 1/sqrt(128)
    char* pbase = (char*)&Ps[wave][0][0];

    for (int kt = 0; kt <= qtile; kt++) {
        // Stage K tile (64x128 bf16) and V slice (128x64 bf16), linear LDS,
        // inverse-swizzled global source (granule ^= row&7).
#pragma unroll
        for (int i = 0; i < 4; i++) {
            int r = wave * 16 + i * 4 + (lane >> 4);          // K local row 0..63
            int g = (lane & 15) ^ (r & 7);
            gload_lds16(&Kh[(size_t)(kt * 64 + r) * D_ + g * 8], &Ks[wave * 16 + i * 4][0]);
        }
#pragma unroll
        for (int i = 0; i < 4; i++) {
            int r = wave * 32 + i * 8 + (lane >> 3);          // V d-row 0..127
            int g = (lane & 7) ^ (r & 7);
            gload_lds16(&Vh[(size_t)r * S_ + kt * 64 + g * 8], &Vs[wave * 32 + i * 8][0]);
        }
        __syncthreads();

        // S = Q K^T (per wave: 16 rows x 64 cols)
        floatx4 sc[4];
#pragma unroll
        for (int ct = 0; ct < 4; ct++) sc[ct] = (floatx4)(0.f);
        __builtin_amdgcn_s_setprio(1);
#pragma unroll
        for (int ks = 0; ks < 4; ks++) {
#pragma unroll
            for (int ct = 0; ct < 4; ct++) {
                int r = ct * 16 + l16;
                short8 kf = *(const short8*)((const char*)Ks + r * 256 +
                                             ((((ks << 2) + quad) ^ (r & 7)) << 4));
                sc[ct] = __builtin_amdgcn_mfma_f32_16x16x32_bf16(qf[ks], kf, sc[ct], 0, 0, 0);
            }
        }
        __builtin_amdgcn_s_setprio(0);
        // scale + causal mask
        int rowbase = qtile * 64 + wave * 16 + quad * 4;
#pragma unroll
        for (int ct = 0; ct < 4; ct++) {
            int col = kt * 64 + ct * 16 + l16;
#pragma unroll
            for (int rr = 0; rr < 4; rr++) {
                float x = sc[ct][rr] * scale;
                sc[ct][rr] = (col > rowbase + rr) ? NEG_S : x;
            }
        }
        // online softmax (row reductions across 16 lanes of each quad-row)
        float alpha[4];
#pragma unroll
        for (int rr = 0; rr < 4; rr++) {
            float mx = fmaxf(fmaxf(sc[0][rr], sc[1][rr]), fmaxf(sc[2][rr], sc[3][rr]));
            mx = fmaxf(mx, __shfl_xor(mx, 1));
            mx = fmaxf(mx, __shfl_xor(mx, 2));
            mx = fmaxf(mx, __shfl_xor(mx, 4));
            mx = fmaxf(mx, __shfl_xor(mx, 8));
            float mnew = fmaxf(mrow[rr], mx);
            alpha[rr] = exp2f((mrow[rr] - mnew) * LOG2E);
            mrow[rr] = mnew;
        }
#pragma unroll
        for (int rr = 0; rr < 4; rr++) {
            float ps = 0.f;
#pragma unroll
            for (int ct = 0; ct < 4; ct++) {
                float p = exp2f((sc[ct][rr] - mrow[rr]) * LOG2E);
                sc[ct][rr] = p;
                ps += p;
            }
            ps += __shfl_xor(ps, 1);
            ps += __shfl_xor(ps, 2);
            ps += __shfl_xor(ps, 4);
            ps += __shfl_xor(ps, 8);
            lrow[rr] = lrow[rr] * alpha[rr] + ps;
        }
#pragma unroll
        for (int c8 = 0; c8 < 8; c8++)
#pragma unroll
            for (int rr = 0; rr < 4; rr++) O[c8][rr] *= alpha[rr];

        // P: C-layout -> per-wave LDS slice (XOR-swizzled 16B granules)
#pragma unroll
        for (int ct = 0; ct < 4; ct++)
#pragma unroll
            for (int rr = 0; rr < 4; rr++) {
                int row = quad * 4 + rr;
                int byteoff = (row << 7) + (((ct * 16 + l16) << 1) ^ ((row & 7) << 4));
                *(unsigned short*)(pbase + byteoff) = f2bf(sc[ct][rr]);
            }
        asm volatile("s_waitcnt lgkmcnt(0)" ::: "memory");
        __builtin_amdgcn_sched_barrier(0);

        // O += P V
        __builtin_amdgcn_s_setprio(1);
#pragma unroll
        for (int ka2 = 0; ka2 < 2; ka2++) {
            int pboff = (l16 << 7) + ((ka2 * 64 + quad * 16) ^ ((l16 & 7) << 4));
            short8 pa = *(const short8*)(pbase + pboff);
#pragma unroll
            for (int c8 = 0; c8 < 8; c8++) {
                int r = c8 * 16 + l16;
                short8 vf = *(const short8*)((const char*)Vs + r * 128 +
                                             ((((ka2 << 2) + quad) ^ (r & 7)) << 4));
                O[c8] = __builtin_amdgcn_mfma_f32_16x16x32_bf16(pa, vf, O[c8], 0, 0, 0);
            }
        }
        __builtin_amdgcn_s_setprio(0);
        asm volatile("s_waitcnt lgkmcnt(0)" ::: "memory");
        __builtin_amdgcn_sched_barrier(0);
        __syncthreads();   // all Ks/Vs/Ps reads done before restage
    }

    // normalize + store bf16 (full-batch layout)
#pragma unroll
    for (int rr = 0; rr < 4; rr++) {
        float inv = 1.f / lrow[rr];
        int row = qtile * 64 + wave * 16 + quad * 4 + rr;
#pragma unroll
        for (int c8 = 0; c8 < 8; c8++) {
            int d = c8 * 16 + l16;
            Omid[((size_t)b * S_ + row) * E_ + h * D_ + d] = f2bf(O[c8][rr] * inv);
        }
    }
}

// =================== legacy fallback kernels (previous passing version) ====

__global__ __launch_bounds__(256) void gemm_bt(const void* __restrict__ A,
                                               const float* __restrict__ Bw,
                                               void* __restrict__ dst,
                                               int aBf16, int dstMode) {
    __shared__ __align__(16) unsigned short As[64][40];
    __shared__ __align__(16) unsigned short Bs[64][40];
    int t = threadIdx.x;
    int wave = t >> 6, lane = t & 63;
    int quad = lane >> 4, l16 = lane & 15;
    floatx4 acc[4];
#pragma unroll
    for (int i = 0; i < 4; i++) acc[i] = (floatx4)(0.f);

    int r = t >> 2, kc = (t & 3) * 8;
    int ra = blockIdx.x * 64 + r;
    int rb = blockIdx.y * 64 + r;

    for (int k0 = 0; k0 < E_; k0 += 32) {
        if (aBf16) {
            const unsigned short* Ab = (const unsigned short*)A + (size_t)ra * E_ + kc + k0;
            *(uint4*)&As[r][kc] = *(const uint4*)Ab;
        } else {
            const float* Af = (const float*)A + (size_t)ra * E_ + kc + k0;
            float4 f0 = *(const float4*)Af;
            float4 f1 = *(const float4*)(Af + 4);
            unsigned short u[8] = {f2bf(f0.x), f2bf(f0.y), f2bf(f0.z), f2bf(f0.w),
                                   f2bf(f1.x), f2bf(f1.y), f2bf(f1.z), f2bf(f1.w)};
            *(uint4*)&As[r][kc] = *(uint4*)u;
        }
        {
            const float* Bf = Bw + (size_t)rb * E_ + kc + k0;
            float4 g0 = *(const float4*)Bf;
            float4 g1 = *(const float4*)(Bf + 4);
            unsigned short u[8] = {f2bf(g0.x), f2bf(g0.y), f2bf(g0.z), f2bf(g0.w),
                                   f2bf(g1.x), f2bf(g1.y), f2bf(g1.z), f2bf(g1.w)};
            *(uint4*)&Bs[r][kc] = *(uint4*)u;
        }
        __syncthreads();
        short8 a = *(const short8*)&As[wave * 16 + l16][quad * 8];
#pragma unroll
        for (int ct = 0; ct < 4; ct++) {
            short8 bfr = *(const short8*)&Bs[ct * 16 + l16][quad * 8];
            acc[ct] = __builtin_amdgcn_mfma_f32_16x16x32_bf16(a, bfr, acc[ct], 0, 0, 0);
        }
        __syncthreads();
    }
#pragma unroll
    for (int ct = 0; ct < 4; ct++) {
#pragma unroll
        for (int rr = 0; rr < 4; rr++) {
            int m = blockIdx.x * 64 + wave * 16 + quad * 4 + rr;
            int n = blockIdx.y * 64 + ct * 16 + l16;
            float val = acc[ct][rr];
            if (dstMode == 0) {
                ((float*)dst)[(size_t)m * E_ + n] = val;
            } else if (dstMode == 1) {
                int b = m >> 11, s = m & 2047, h = n >> 7, d = n & 127;
                ((float*)dst)[(((size_t)(b * H_ + h)) * S_ + s) * D_ + d] = val;
            } else {
                ((unsigned short*)dst)[(size_t)m * E_ + n] = f2bf(val);
            }
        }
    }
}

__global__ __launch_bounds__(256) void attn_fwd(const unsigned short* __restrict__ Qf,
                                                const float* __restrict__ Kb0,
                                                const float* __restrict__ Vb0,
                                                const float* __restrict__ cosT,
                                                const float* __restrict__ sinT,
                                                unsigned short* __restrict__ Omid,
                                                int qtile0) {
    __shared__ __align__(16) unsigned short Ks[64][136];
    __shared__ __align__(16) unsigned short Vt[128][72];
    __shared__ __align__(16) unsigned short Ps[4][16][72];

    int t = threadIdx.x;
    int wave = t >> 6, lane = t & 63;
    int quad = lane >> 4, l16 = lane & 15;
    int qtile = qtile0 + blockIdx.x, h = blockIdx.y;
    const float* Kb = Kb0 + (size_t)h * S_ * D_;
    const float* Vb = Vb0 + (size_t)h * S_ * D_;

    int sq = qtile * 64 + wave * 16 + l16;
    short8 qf[4];
#pragma unroll
    for (int ks = 0; ks < 4; ks++) {
        int d0 = ks * 32 + quad * 8;
        union { uint4 u4; unsigned short u[8]; } un;
        un.u4 = *(const uint4*)&Qf[(size_t)sq * E_ + h * D_ + d0];
#pragma unroll
        for (int i = 0; i < 4; i++) {
            int j = (d0 >> 1) + i;
            float c = cosT[sq * 64 + j], s = sinT[sq * 64 + j];
            float x1 = bf2f(un.u[2 * i]), x2 = bf2f(un.u[2 * i + 1]);
            un.u[2 * i] = f2bf(x1 * c - x2 * s);
            un.u[2 * i + 1] = f2bf(x1 * s + x2 * c);
        }
        qf[ks] = *(short8*)un.u;
    }

    floatx4 O[8];
#pragma unroll
    for (int i = 0; i < 8; i++) O[i] = (floatx4)(0.f);
    float mrow[4], lrow[4];
#pragma unroll
    for (int r = 0; r < 4; r++) { mrow[r] = NEG_S; lrow[r] = 0.f; }

    const float scale = 0.08838834764831845f;

    for (int kt = 0; kt <= qtile; kt++) {
        __syncthreads();
        int r = t >> 2;
#pragma unroll
        for (int it = 0; it < 4; it++) {
            int d0 = (t & 3) * 8 + it * 32;
            int sk = kt * 64 + r;
            float4 ka = *(const float4*)&Kb[(size_t)sk * D_ + d0];
            float4 kb2 = *(const float4*)&Kb[(size_t)sk * D_ + d0 + 4];
            float xs[8] = {ka.x, ka.y, ka.z, ka.w, kb2.x, kb2.y, kb2.z, kb2.w};
            unsigned short u[8];
#pragma unroll
            for (int i = 0; i < 4; i++) {
                int j = (d0 >> 1) + i;
                float c = cosT[sk * 64 + j], s = sinT[sk * 64 + j];
                float x1 = xs[2 * i], x2 = xs[2 * i + 1];
                u[2 * i]     = f2bf(x1 * c - x2 * s);
                u[2 * i + 1] = f2bf(x1 * s + x2 * c);
            }
            *(uint4*)&Ks[r][d0] = *(uint4*)u;
            float4 va = *(const float4*)&Vb[(size_t)sk * D_ + d0];
            float4 vb2 = *(const float4*)&Vb[(size_t)sk * D_ + d0 + 4];
            float vs[8] = {va.x, va.y, va.z, va.w, vb2.x, vb2.y, vb2.z, vb2.w};
#pragma unroll
            for (int i = 0; i < 8; i++) Vt[d0 + i][r] = f2bf(vs[i]);
        }
        __syncthreads();

        floatx4 sc[4];
#pragma unroll
        for (int ct = 0; ct < 4; ct++) sc[ct] = (floatx4)(0.f);
#pragma unroll
        for (int ks = 0; ks < 4; ks++) {
#pragma unroll
            for (int ct = 0; ct < 4; ct++) {
                short8 kf = *(const short8*)&Ks[ct * 16 + l16][ks * 32 + quad * 8];
                sc[ct] = __builtin_amdgcn_mfma_f32_16x16x32_bf16(qf[ks], kf, sc[ct], 0, 0, 0);
            }
        }
        int rowbase = qtile * 64 + wave * 16 + quad * 4;
#pragma unroll
        for (int ct = 0; ct < 4; ct++) {
            int col = kt * 64 + ct * 16 + l16;
#pragma unroll
            for (int rr = 0; rr < 4; rr++) {
                float x = sc[ct][rr] * scale;
                sc[ct][rr] = (col > rowbase + rr) ? NEG_S : x;
            }
        }
        float alpha[4];
#pragma unroll
        for (int rr = 0; rr < 4; rr++) {
            float mx = fmaxf(fmaxf(sc[0][rr], sc[1][rr]), fmaxf(sc[2][rr], sc[3][rr]));
            mx = fmaxf(mx, __shfl_xor(mx, 1));
            mx = fmaxf(mx, __shfl_xor(mx, 2));
            mx = fmaxf(mx, __shfl_xor(mx, 4));
            mx = fmaxf(mx, __shfl_xor(mx, 8));
            float mnew = fmaxf(mrow[rr], mx);
            alpha[rr] = exp2f((mrow[rr] - mnew) * LOG2E);
            mrow[rr] = mnew;
        }
#pragma unroll
        for (int rr = 0; rr < 4; rr++) {
            float ps = 0.f;
#pragma unroll
            for (int ct = 0; ct < 4; ct++) {
                float p = exp2f((sc[ct][rr] - mrow[rr]) * LOG2E);
                sc[ct][rr] = p;
                ps += p;
            }
            ps += __shfl_xor(ps, 1);
            ps += __shfl_xor(ps, 2);
            ps += __shfl_xor(ps, 4);
            ps += __shfl_xor(ps, 8);
            lrow[rr] = lrow[rr] * alpha[rr] + ps;
        }
#pragma unroll
        for (int c8 = 0; c8 < 8; c8++)
#pragma unroll
            for (int rr = 0; rr < 4; rr++) O[c8][rr] *= alpha[rr];

#pragma unroll
        for (int ct = 0; ct < 4; ct++)
#pragma unroll
            for (int rr = 0; rr < 4; rr++)
                Ps[wave][quad * 4 + rr][ct * 16 + l16] = f2bf(sc[ct][rr]);
        __syncthreads();

#pragma unroll
        for (int ka2 = 0; ka2 < 2; ka2++) {
            short8 pa = *(const short8*)&Ps[wave][l16][ka2 * 32 + quad * 8];
#pragma unroll
            for (int c8 = 0; c8 < 8; c8++) {
                short8 vf = *(const short8*)&Vt[c8 * 16 + l16][ka2 * 32 + quad * 8];
                O[c8] = __builtin_amdgcn_mfma_f32_16x16x32_bf16(pa, vf, O[c8], 0, 0, 0);
            }
        }
    }

#pragma unroll
    for (int rr = 0; rr < 4; rr++) {
        float inv = 1.f / lrow[rr];
        int lrw = blockIdx.x * 64 + wave * 16 + quad * 4 + rr;
#pragma unroll
        for (int c8 = 0; c8 < 8; c8++) {
            int d = c8 * 16 + l16;
            Omid[(size_t)lrw * E_ + h * D_ + d] = f2bf(O[c8][rr] * inv);
        }
    }
}

extern "C" void kernel_launch(void* const* d_in, const int* in_sizes, int n_in,
                              void* d_out, int out_size, void* d_ws, size_t ws_size,
                              hipStream_t stream) {
    const float* x  = (const float*)d_in[0];
    const float* Wq = (const float*)d_in[1];
    const float* Wk = (const float*)d_in[2];
    const float* Wv = (const float*)d_in[3];
    const float* Wo = (const float*)d_in[4];

    float* out_attn = (float*)d_out;                              // (B,S,E) fp32
    float* out_k = out_attn + (size_t)B_ * H_ * S_ * D_;          // (B,H,S,D) fp32 pre-rope
    float* out_v = out_k + (size_t)B_ * H_ * S_ * D_;             // (B,H,S,D) fp32

    char* ws = (char*)d_ws;
    float* cosT = (float*)ws;
    float* sinT = cosT + S_ * (D_ / 2);
    size_t tab_bytes = 2u * S_ * (D_ / 2) * sizeof(float);        // 1 MB

    size_t krBytes  = (size_t)B_ * H_ * S_ * D_ * 2;              // 16.8 MB
    size_t wbBytes  = (size_t)E_ * E_ * 2;                        // 8.4 MB
    size_t midBytes = (size_t)B_ * S_ * E_ * 2;                   // 16.8 MB
    size_t needFast = tab_bytes + 2 * krBytes + wbBytes + midBytes; // ~59.8 MB

    hipLaunchKernelGGL(rope_tab, dim3(512), dim3(256), 0, stream, cosT, sinT);

    if (ws_size >= needFast) {
        // ---------------- fast path ----------------
        unsigned short* Kr  = (unsigned short*)(ws + tab_bytes);
        unsigned short* Vt  = Kr + (size_t)B_ * H_ * S_ * D_;
        unsigned short* Wb  = Vt + (size_t)B_ * H_ * S_ * D_;
        unsigned short* mid = Wb + (size_t)E_ * E_;
        unsigned short* xb    = (unsigned short*)out_attn;                       // [0,16.8M)
        unsigned short* q_tmp = (unsigned short*)(out_attn + (size_t)S_ * E_);   // [16.8,33.5M)

        hipLaunchKernelGGL(cvt_bf16, dim3(4096), dim3(256), 0, stream, x, xb, 1048576);

        hipLaunchKernelGGL(cvt_bf16, dim3(2048), dim3(256), 0, stream, Wq, Wb, 524288);
        hipLaunchKernelGGL(gemm128, dim3(32, 16), dim3(256), 0, stream, xb, Wb, (void*)q_tmp, 3);

        hipLaunchKernelGGL(cvt_bf16, dim3(2048), dim3(256), 0, stream, Wk, Wb, 524288);
        hipLaunchKernelGGL(gemm128, dim3(32, 16), dim3(256), 0, stream, xb, Wb, (void*)out_k, 1);
        hipLaunchKernelGGL(prep_k, dim3(4096), dim3(256), 0, stream, out_k, Kr, cosT, sinT);

        hipLaunchKernelGGL(cvt_bf16, dim3(2048), dim3(256), 0, stream, Wv, Wb, 524288);
        hipLaunchKernelGGL(gemm128, dim3(32, 16), dim3(256), 0, stream, xb, Wb, (void*)out_v, 1);
        hipLaunchKernelGGL(prep_v, dim3(32, 32), dim3(256), 0, stream, out_v, Vt);

        hipLaunchKernelGGL(cvt_bf16, dim3(2048), dim3(256), 0, stream, Wo, Wb, 524288);

        hipLaunchKernelGGL(attn_fast6, dim3(512, B_), dim3(256), 0, stream,
                           q_tmp, Kr, Vt, cosT, sinT, mid);
        hipLaunchKernelGGL(gemm128, dim3(32, 16), dim3(256), 0, stream, mid, Wb,
                           (void*)out_attn, 0);
    } else {
        // ---------------- legacy fallback (previous passing version) -------
        unsigned short* q_tmp = (unsigned short*)(out_attn + (size_t)S_ * E_);
        unsigned short* mid = (unsigned short*)(ws + tab_bytes);
        size_t avail = ws_size > tab_bytes ? ws_size - tab_bytes : 0;
        int R = 64;
        for (int r = 2048; r >= 64; r >>= 1) {
            if ((size_t)r * E_ * 2 <= avail) { R = r; break; }
        }

        dim3 gg(64, 32);
        hipLaunchKernelGGL(gemm_bt, gg, dim3(256), 0, stream, (const void*)x, Wq, (void*)q_tmp, 0, 3);
        hipLaunchKernelGGL(gemm_bt, gg, dim3(256), 0, stream, (const void*)x, Wk, (void*)out_k, 0, 1);
        hipLaunchKernelGGL(gemm_bt, gg, dim3(256), 0, stream, (const void*)x, Wv, (void*)out_v, 0, 1);

        const size_t bhsd = (size_t)H_ * S_ * D_;
        for (int b = 0; b < B_; b++) {
            const unsigned short* qb = q_tmp + (size_t)b * S_ * E_;
            for (int c = 0; c < S_ / 64; c += R / 64) {
                hipLaunchKernelGGL(attn_fwd, dim3(R / 64, H_), dim3(256), 0, stream,
                                   qb, out_k + b * bhsd, out_v + b * bhsd,
                                   cosT, sinT, mid, c);
                hipLaunchKernelGGL(gemm_bt, dim3(R / 64, 32), dim3(256), 0, stream,
                                   (const void*)mid, Wo,
                                   (void*)(out_attn + ((size_t)b * S_ + c * 64) * E_), 1, 0);
            }
        }
    }
}

// Round 7
// 487.903 us; speedup vs baseline: 1.2767x; 1.0944x over previous
//
#include <hip/hip_runtime.h>

typedef __attribute__((ext_vector_type(8))) short short8;
typedef __attribute__((ext_vector_type(4))) float floatx4;

#define B_ 2
#define S_ 2048
#define E_ 2048
#define H_ 16
#define D_ 128

#define NEG_S  (-3.0e4f)
#define LOG2E  1.4426950408889634f

__device__ inline float bf2f(unsigned short u) {
    union { unsigned int i; float f; } v; v.i = ((unsigned int)u) << 16; return v.f;
}
__device__ inline unsigned short f2bf(float f) {
    union { float f; unsigned int i; } v; v.f = f;
    unsigned int r = v.i + 0x7FFFu + ((v.i >> 16) & 1u);
    return (unsigned short)(r >> 16);
}

// async global->LDS, 16B per lane. LDS dest is wave-uniform base + lane*16.
__device__ inline void gload_lds16(const void* g, void* l) {
    __builtin_amdgcn_global_load_lds((__attribute__((address_space(1))) void*)(void*)g,
                                     (__attribute__((address_space(3))) void*)l, 16, 0, 0);
}

// Precompute RoPE cos/sin tables: [S][D/2] fp32. 1 MB total.
__global__ void rope_tab(float* __restrict__ cosT, float* __restrict__ sinT) {
    int idx = blockIdx.x * 256 + threadIdx.x;   // 2048*64 entries
    int s = idx >> 6, j = idx & 63;
    float inv = exp2f(-(float)(2 * j) * (13.287712379549449f / 128.0f));
    float ang = (float)s * inv;
    cosT[idx] = cosf(ang);
    sinT[idx] = sinf(ang);
}

// fp32 -> bf16, 8 elems/thread, exact-sized grids.
__global__ __launch_bounds__(256) void cvt_bf16(const float* __restrict__ in,
                                                unsigned short* __restrict__ out, int n8) {
    int i = blockIdx.x * 256 + threadIdx.x;
    if (i >= n8) return;
    float4 f0 = *(const float4*)(in + (size_t)i * 8);
    float4 f1 = *(const float4*)(in + (size_t)i * 8 + 4);
    unsigned short u[8] = {f2bf(f0.x), f2bf(f0.y), f2bf(f0.z), f2bf(f0.w),
                           f2bf(f1.x), f2bf(f1.y), f2bf(f1.z), f2bf(f1.w)};
    *(uint4*)(out + (size_t)i * 8) = *(uint4*)u;
}

// out_k fp32 [B][H][S][D] -> Kr bf16 same layout, RoPE applied once.
__global__ __launch_bounds__(256) void prep_k(const float* __restrict__ K,
                                              unsigned short* __restrict__ Kr,
                                              const float* __restrict__ cosT,
                                              const float* __restrict__ sinT) {
    int idx = blockIdx.x * 256 + threadIdx.x;   // B*H*S*16 = 1,048,576
    int g = idx & 15;
    int s = (idx >> 4) & (S_ - 1);
    const float* src = K + (size_t)idx * 8;
    float4 f0 = *(const float4*)src;
    float4 f1 = *(const float4*)(src + 4);
    float xs[8] = {f0.x, f0.y, f0.z, f0.w, f1.x, f1.y, f1.z, f1.w};
    unsigned short u[8];
    int jb = g * 4;
#pragma unroll
    for (int i = 0; i < 4; i++) {
        float c = cosT[s * 64 + jb + i], sn = sinT[s * 64 + jb + i];
        float x1 = xs[2 * i], x2 = xs[2 * i + 1];
        u[2 * i]     = f2bf(x1 * c - x2 * sn);
        u[2 * i + 1] = f2bf(x1 * sn + x2 * c);
    }
    *(uint4*)(Kr + (size_t)idx * 8) = *(uint4*)u;
}

// out_v fp32 [B][H][S][D] -> Vt bf16 [B][H][D][S] (transposed via LDS).
__global__ __launch_bounds__(256) void prep_v(const float* __restrict__ V,
                                              unsigned short* __restrict__ Vt) {
    __shared__ unsigned short Ls[64][130];
    int bh = blockIdx.y;
    int s0 = blockIdx.x * 64;
    int t = threadIdx.x;
    const float* src = V + ((size_t)bh * S_ + s0) * D_;
#pragma unroll
    for (int it = 0; it < 4; it++) {
        int r = it * 16 + (t >> 4), d0 = (t & 15) * 8;
        float4 f0 = *(const float4*)&src[(size_t)r * D_ + d0];
        float4 f1 = *(const float4*)&src[(size_t)r * D_ + d0 + 4];
        unsigned short u[8] = {f2bf(f0.x), f2bf(f0.y), f2bf(f0.z), f2bf(f0.w),
                               f2bf(f1.x), f2bf(f1.y), f2bf(f1.z), f2bf(f1.w)};
#pragma unroll
        for (int i = 0; i < 8; i++) Ls[r][d0 + i] = u[i];
    }
    __syncthreads();
    unsigned short* dst = Vt + (size_t)bh * D_ * S_;
#pragma unroll
    for (int it = 0; it < 4; it++) {
        int d = it * 32 + (t >> 3), ss = (t & 7) * 8;
        unsigned short u[8];
#pragma unroll
        for (int i = 0; i < 8; i++) u[i] = Ls[ss + i][d];
        *(uint4*)&dst[(size_t)d * S_ + s0 + ss] = *(uint4*)u;
    }
}

// ---- gemm128 v2: 128x128 tile, BK=64, double-buffered LDS (64KB), ONE
// barrier per K-step. STAGE(next buf) issued before compute(cur); the
// barrier's implicit vmcnt(0)+lgkmcnt(0) drain lands after 32 MFMA/wave of
// compute (catalog T3-minimum 2-phase). Row layout [128][64] bf16 = 128B/row,
// 8x16B granules, XOR-swizzled by (row&7) -- same pattern as attn Vs (proven).
__global__ __launch_bounds__(256) void gemm128(const unsigned short* __restrict__ A,
                                               const unsigned short* __restrict__ Bw,
                                               void* __restrict__ dst, int dstMode) {
    __shared__ __align__(16) unsigned short As[2][128][64];
    __shared__ __align__(16) unsigned short Bs[2][128][64];
    int t = threadIdx.x;
    int wave = t >> 6, lane = t & 63;
    int quad = lane >> 4, l16 = lane & 15;
    int wr = wave >> 1, wc = wave & 1;

    floatx4 acc[4][4];
#pragma unroll
    for (int m = 0; m < 4; m++)
#pragma unroll
        for (int n = 0; n < 4; n++) acc[m][n] = (floatx4)(0.f);

    const size_t aRow0 = (size_t)blockIdx.x * 128;
    const size_t bRow0 = (size_t)blockIdx.y * 128;

    // staging geometry: 64 lanes x 16B = 8 rows of 128B per instr;
    // lane -> (row = base + lane>>3, granule = lane&7), source granule
    // pre-swizzled by ^(row&7) so LDS stays linear.
#define GSTAGE(BUF, K0)                                                          \
    {                                                                            \
        _Pragma("unroll")                                                        \
        for (int i_ = 0; i_ < 4; i_++) {                                         \
            int r_ = wave * 32 + i_ * 8 + (lane >> 3);                           \
            int g_ = (lane & 7) ^ (r_ & 7);                                      \
            gload_lds16(A + (aRow0 + r_) * E_ + (K0) + g_ * 8,                   \
                        &As[BUF][wave * 32 + i_ * 8][0]);                        \
            gload_lds16(Bw + (bRow0 + r_) * E_ + (K0) + g_ * 8,                  \
                        &Bs[BUF][wave * 32 + i_ * 8][0]);                        \
        }                                                                        \
    }

    GSTAGE(0, 0);
    __syncthreads();

    for (int it = 0; it < E_ / 64; it++) {
        int cur = it & 1;
        if (it + 1 < E_ / 64) GSTAGE(cur ^ 1, (it + 1) * 64);

        __builtin_amdgcn_s_setprio(1);
#pragma unroll
        for (int ks = 0; ks < 2; ks++) {
            short8 af[4], bfr[4];
#pragma unroll
            for (int m = 0; m < 4; m++) {
                int r = wr * 64 + m * 16 + l16;
                af[m] = *(const short8*)((const char*)&As[cur][0][0] + r * 128 +
                                         ((((ks << 2) + quad) ^ (r & 7)) << 4));
            }
#pragma unroll
            for (int n = 0; n < 4; n++) {
                int r = wc * 64 + n * 16 + l16;
                bfr[n] = *(const short8*)((const char*)&Bs[cur][0][0] + r * 128 +
                                          ((((ks << 2) + quad) ^ (r & 7)) << 4));
            }
#pragma unroll
            for (int m = 0; m < 4; m++)
#pragma unroll
                for (int n = 0; n < 4; n++)
                    acc[m][n] = __builtin_amdgcn_mfma_f32_16x16x32_bf16(af[m], bfr[n], acc[m][n], 0, 0, 0);
        }
        __builtin_amdgcn_s_setprio(0);
        __syncthreads();   // drains prefetch vmcnt + all cur reads
    }
#undef GSTAGE

#pragma unroll
    for (int m = 0; m < 4; m++)
#pragma unroll
        for (int n = 0; n < 4; n++)
#pragma unroll
            for (int rr = 0; rr < 4; rr++) {
                int mg = (int)aRow0 + wr * 64 + m * 16 + quad * 4 + rr;
                int ng = (int)bRow0 + wc * 64 + n * 16 + l16;
                float val = acc[m][n][rr];
                if (dstMode == 0) {
                    ((float*)dst)[(size_t)mg * E_ + ng] = val;
                } else if (dstMode == 1) {
                    int b = mg >> 11, s = mg & 2047, h = ng >> 7, d = ng & 127;
                    ((float*)dst)[(((size_t)(b * H_ + h)) * S_ + s) * D_ + d] = val;
                } else {
                    ((unsigned short*)dst)[(size_t)mg * E_ + ng] = f2bf(val);
                }
            }
}

// ---- Flash attention v6 (unchanged from round 6: 151us measured).
__global__ __launch_bounds__(256) void attn_fast6(const unsigned short* __restrict__ Qf,
                                                  const unsigned short* __restrict__ Kr,
                                                  const unsigned short* __restrict__ Vt,
                                                  const float* __restrict__ cosT,
                                                  const float* __restrict__ sinT,
                                                  unsigned short* __restrict__ Omid) {
    __shared__ __align__(16) unsigned short Ks[64][128];
    __shared__ __align__(16) unsigned short Vs[128][64];
    __shared__ __align__(16) unsigned short Ps[4][16][64];   // XOR-swizzled granules

    int t = threadIdx.x;
    int wave = t >> 6, lane = t & 63;
    int quad = lane >> 4, l16 = lane & 15;
    int orig = blockIdx.x;                      // 0..511
    int L = (orig & 7) * 64 + (orig >> 3);      // XCD-chunked bijection
    int h = L >> 5;                             // 2 heads per XCD (L2-resident K/V)
    int q5 = L & 31;
    int qtile = (h & 1) ? (31 - q5) : q5;       // CU-level LPT: pair (q, 31-q)
    int b = blockIdx.y;

    const unsigned short* Qb = Qf + (size_t)b * S_ * E_;
    const unsigned short* Kh = Kr + ((size_t)(b * H_ + h)) * S_ * D_;
    const unsigned short* Vh = Vt + ((size_t)(b * H_ + h)) * D_ * S_;

    int sq = qtile * 64 + wave * 16 + l16;
    short8 qf[4];
#pragma unroll
    for (int ks = 0; ks < 4; ks++) {
        int d0 = ks * 32 + quad * 8;
        union { uint4 u4; unsigned short u[8]; } un;
        un.u4 = *(const uint4*)&Qb[(size_t)sq * E_ + h * D_ + d0];
#pragma unroll
        for (int i = 0; i < 4; i++) {
            int j = (d0 >> 1) + i;
            float c = cosT[sq * 64 + j], s = sinT[sq * 64 + j];
            float x1 = bf2f(un.u[2 * i]), x2 = bf2f(un.u[2 * i + 1]);
            un.u[2 * i] = f2bf(x1 * c - x2 * s);
            un.u[2 * i + 1] = f2bf(x1 * s + x2 * c);
        }
        qf[ks] = *(short8*)un.u;
    }

    floatx4 O[8];
#pragma unroll
    for (int i = 0; i < 8; i++) O[i] = (floatx4)(0.f);
    float mrow[4], lrow[4];
#pragma unroll
    for (int r = 0; r < 4; r++) { mrow[r] = NEG_S; lrow[r] = 0.f; }

    const float scale = 0.08838834764831845f; // 1/sqrt(128)
    char* pbase = (char*)&Ps[wave][0][0];

    for (int kt = 0; kt <= qtile; kt++) {
#pragma unroll
        for (int i = 0; i < 4; i++) {
            int r = wave * 16 + i * 4 + (lane >> 4);          // K local row 0..63
            int g = (lane & 15) ^ (r & 7);
            gload_lds16(&Kh[(size_t)(kt * 64 + r) * D_ + g * 8], &Ks[wave * 16 + i * 4][0]);
        }
#pragma unroll
        for (int i = 0; i < 4; i++) {
            int r = wave * 32 + i * 8 + (lane >> 3);          // V d-row 0..127
            int g = (lane & 7) ^ (r & 7);
            gload_lds16(&Vh[(size_t)r * S_ + kt * 64 + g * 8], &Vs[wave * 32 + i * 8][0]);
        }
        __syncthreads();

        floatx4 sc[4];
#pragma unroll
        for (int ct = 0; ct < 4; ct++) sc[ct] = (floatx4)(0.f);
        __builtin_amdgcn_s_setprio(1);
#pragma unroll
        for (int ks = 0; ks < 4; ks++) {
#pragma unroll
            for (int ct = 0; ct < 4; ct++) {
                int r = ct * 16 + l16;
                short8 kf = *(const short8*)((const char*)Ks + r * 256 +
                                             ((((ks << 2) + quad) ^ (r & 7)) << 4));
                sc[ct] = __builtin_amdgcn_mfma_f32_16x16x32_bf16(qf[ks], kf, sc[ct], 0, 0, 0);
            }
        }
        __builtin_amdgcn_s_setprio(0);
        int rowbase = qtile * 64 + wave * 16 + quad * 4;
#pragma unroll
        for (int ct = 0; ct < 4; ct++) {
            int col = kt * 64 + ct * 16 + l16;
#pragma unroll
            for (int rr = 0; rr < 4; rr++) {
                float x = sc[ct][rr] * scale;
                sc[ct][rr] = (col > rowbase + rr) ? NEG_S : x;
            }
        }
        float alpha[4];
#pragma unroll
        for (int rr = 0; rr < 4; rr++) {
            float mx = fmaxf(fmaxf(sc[0][rr], sc[1][rr]), fmaxf(sc[2][rr], sc[3][rr]));
            mx = fmaxf(mx, __shfl_xor(mx, 1));
            mx = fmaxf(mx, __shfl_xor(mx, 2));
            mx = fmaxf(mx, __shfl_xor(mx, 4));
            mx = fmaxf(mx, __shfl_xor(mx, 8));
            float mnew = fmaxf(mrow[rr], mx);
            alpha[rr] = exp2f((mrow[rr] - mnew) * LOG2E);
            mrow[rr] = mnew;
        }
#pragma unroll
        for (int rr = 0; rr < 4; rr++) {
            float ps = 0.f;
#pragma unroll
            for (int ct = 0; ct < 4; ct++) {
                float p = exp2f((sc[ct][rr] - mrow[rr]) * LOG2E);
                sc[ct][rr] = p;
                ps += p;
            }
            ps += __shfl_xor(ps, 1);
            ps += __shfl_xor(ps, 2);
            ps += __shfl_xor(ps, 4);
            ps += __shfl_xor(ps, 8);
            lrow[rr] = lrow[rr] * alpha[rr] + ps;
        }
#pragma unroll
        for (int c8 = 0; c8 < 8; c8++)
#pragma unroll
            for (int rr = 0; rr < 4; rr++) O[c8][rr] *= alpha[rr];

#pragma unroll
        for (int ct = 0; ct < 4; ct++)
#pragma unroll
            for (int rr = 0; rr < 4; rr++) {
                int row = quad * 4 + rr;
                int byteoff = (row << 7) + (((ct * 16 + l16) << 1) ^ ((row & 7) << 4));
                *(unsigned short*)(pbase + byteoff) = f2bf(sc[ct][rr]);
            }
        asm volatile("s_waitcnt lgkmcnt(0)" ::: "memory");
        __builtin_amdgcn_sched_barrier(0);

        __builtin_amdgcn_s_setprio(1);
#pragma unroll
        for (int ka2 = 0; ka2 < 2; ka2++) {
            int pboff = (l16 << 7) + ((ka2 * 64 + quad * 16) ^ ((l16 & 7) << 4));
            short8 pa = *(const short8*)(pbase + pboff);
#pragma unroll
            for (int c8 = 0; c8 < 8; c8++) {
                int r = c8 * 16 + l16;
                short8 vf = *(const short8*)((const char*)Vs + r * 128 +
                                             ((((ka2 << 2) + quad) ^ (r & 7)) << 4));
                O[c8] = __builtin_amdgcn_mfma_f32_16x16x32_bf16(pa, vf, O[c8], 0, 0, 0);
            }
        }
        __builtin_amdgcn_s_setprio(0);
        asm volatile("s_waitcnt lgkmcnt(0)" ::: "memory");
        __builtin_amdgcn_sched_barrier(0);
        __syncthreads();
    }

#pragma unroll
    for (int rr = 0; rr < 4; rr++) {
        float inv = 1.f / lrow[rr];
        int row = qtile * 64 + wave * 16 + quad * 4 + rr;
#pragma unroll
        for (int c8 = 0; c8 < 8; c8++) {
            int d = c8 * 16 + l16;
            Omid[((size_t)b * S_ + row) * E_ + h * D_ + d] = f2bf(O[c8][rr] * inv);
        }
    }
}

// =================== legacy fallback kernels (previous passing version) ====

__global__ __launch_bounds__(256) void gemm_bt(const void* __restrict__ A,
                                               const float* __restrict__ Bw,
                                               void* __restrict__ dst,
                                               int aBf16, int dstMode) {
    __shared__ __align__(16) unsigned short As[64][40];
    __shared__ __align__(16) unsigned short Bs[64][40];
    int t = threadIdx.x;
    int wave = t >> 6, lane = t & 63;
    int quad = lane >> 4, l16 = lane & 15;
    floatx4 acc[4];
#pragma unroll
    for (int i = 0; i < 4; i++) acc[i] = (floatx4)(0.f);

    int r = t >> 2, kc = (t & 3) * 8;
    int ra = blockIdx.x * 64 + r;
    int rb = blockIdx.y * 64 + r;

    for (int k0 = 0; k0 < E_; k0 += 32) {
        if (aBf16) {
            const unsigned short* Ab = (const unsigned short*)A + (size_t)ra * E_ + kc + k0;
            *(uint4*)&As[r][kc] = *(const uint4*)Ab;
        } else {
            const float* Af = (const float*)A + (size_t)ra * E_ + kc + k0;
            float4 f0 = *(const float4*)Af;
            float4 f1 = *(const float4*)(Af + 4);
            unsigned short u[8] = {f2bf(f0.x), f2bf(f0.y), f2bf(f0.z), f2bf(f0.w),
                                   f2bf(f1.x), f2bf(f1.y), f2bf(f1.z), f2bf(f1.w)};
            *(uint4*)&As[r][kc] = *(uint4*)u;
        }
        {
            const float* Bf = Bw + (size_t)rb * E_ + kc + k0;
            float4 g0 = *(const float4*)Bf;
            float4 g1 = *(const float4*)(Bf + 4);
            unsigned short u[8] = {f2bf(g0.x), f2bf(g0.y), f2bf(g0.z), f2bf(g0.w),
                                   f2bf(g1.x), f2bf(g1.y), f2bf(g1.z), f2bf(g1.w)};
            *(uint4*)&Bs[r][kc] = *(uint4*)u;
        }
        __syncthreads();
        short8 a = *(const short8*)&As[wave * 16 + l16][quad * 8];
#pragma unroll
        for (int ct = 0; ct < 4; ct++) {
            short8 bfr = *(const short8*)&Bs[ct * 16 + l16][quad * 8];
            acc[ct] = __builtin_amdgcn_mfma_f32_16x16x32_bf16(a, bfr, acc[ct], 0, 0, 0);
        }
        __syncthreads();
    }
#pragma unroll
    for (int ct = 0; ct < 4; ct++) {
#pragma unroll
        for (int rr = 0; rr < 4; rr++) {
            int m = blockIdx.x * 64 + wave * 16 + quad * 4 + rr;
            int n = blockIdx.y * 64 + ct * 16 + l16;
            float val = acc[ct][rr];
            if (dstMode == 0) {
                ((float*)dst)[(size_t)m * E_ + n] = val;
            } else if (dstMode == 1) {
                int b = m >> 11, s = m & 2047, h = n >> 7, d = n & 127;
                ((float*)dst)[(((size_t)(b * H_ + h)) * S_ + s) * D_ + d] = val;
            } else {
                ((unsigned short*)dst)[(size_t)m * E_ + n] = f2bf(val);
            }
        }
    }
}

__global__ __launch_bounds__(256) void attn_fwd(const unsigned short* __restrict__ Qf,
                                                const float* __restrict__ Kb0,
                                                const float* __restrict__ Vb0,
                                                const float* __restrict__ cosT,
                                                const float* __restrict__ sinT,
                                                unsigned short* __restrict__ Omid,
                                                int qtile0) {
    __shared__ __align__(16) unsigned short Ks[64][136];
    __shared__ __align__(16) unsigned short Vt[128][72];
    __shared__ __align__(16) unsigned short Ps[4][16][72];

    int t = threadIdx.x;
    int wave = t >> 6, lane = t & 63;
    int quad = lane >> 4, l16 = lane & 15;
    int qtile = qtile0 + blockIdx.x, h = blockIdx.y;
    const float* Kb = Kb0 + (size_t)h * S_ * D_;
    const float* Vb = Vb0 + (size_t)h * S_ * D_;

    int sq = qtile * 64 + wave * 16 + l16;
    short8 qf[4];
#pragma unroll
    for (int ks = 0; ks < 4; ks++) {
        int d0 = ks * 32 + quad * 8;
        union { uint4 u4; unsigned short u[8]; } un;
        un.u4 = *(const uint4*)&Qf[(size_t)sq * E_ + h * D_ + d0];
#pragma unroll
        for (int i = 0; i < 4; i++) {
            int j = (d0 >> 1) + i;
            float c = cosT[sq * 64 + j], s = sinT[sq * 64 + j];
            float x1 = bf2f(un.u[2 * i]), x2 = bf2f(un.u[2 * i + 1]);
            un.u[2 * i] = f2bf(x1 * c - x2 * s);
            un.u[2 * i + 1] = f2bf(x1 * s + x2 * c);
        }
        qf[ks] = *(short8*)un.u;
    }

    floatx4 O[8];
#pragma unroll
    for (int i = 0; i < 8; i++) O[i] = (floatx4)(0.f);
    float mrow[4], lrow[4];
#pragma unroll
    for (int r = 0; r < 4; r++) { mrow[r] = NEG_S; lrow[r] = 0.f; }

    const float scale = 0.08838834764831845f;

    for (int kt = 0; kt <= qtile; kt++) {
        __syncthreads();
        int r = t >> 2;
#pragma unroll
        for (int it = 0; it < 4; it++) {
            int d0 = (t & 3) * 8 + it * 32;
            int sk = kt * 64 + r;
            float4 ka = *(const float4*)&Kb[(size_t)sk * D_ + d0];
            float4 kb2 = *(const float4*)&Kb[(size_t)sk * D_ + d0 + 4];
            float xs[8] = {ka.x, ka.y, ka.z, ka.w, kb2.x, kb2.y, kb2.z, kb2.w};
            unsigned short u[8];
#pragma unroll
            for (int i = 0; i < 4; i++) {
                int j = (d0 >> 1) + i;
                float c = cosT[sk * 64 + j], s = sinT[sk * 64 + j];
                float x1 = xs[2 * i], x2 = xs[2 * i + 1];
                u[2 * i]     = f2bf(x1 * c - x2 * s);
                u[2 * i + 1] = f2bf(x1 * s + x2 * c);
            }
            *(uint4*)&Ks[r][d0] = *(uint4*)u;
            float4 va = *(const float4*)&Vb[(size_t)sk * D_ + d0];
            float4 vb2 = *(const float4*)&Vb[(size_t)sk * D_ + d0 + 4];
            float vs[8] = {va.x, va.y, va.z, va.w, vb2.x, vb2.y, vb2.z, vb2.w};
#pragma unroll
            for (int i = 0; i < 8; i++) Vt[d0 + i][r] = f2bf(vs[i]);
        }
        __syncthreads();

        floatx4 sc[4];
#pragma unroll
        for (int ct = 0; ct < 4; ct++) sc[ct] = (floatx4)(0.f);
#pragma unroll
        for (int ks = 0; ks < 4; ks++) {
#pragma unroll
            for (int ct = 0; ct < 4; ct++) {
                short8 kf = *(const short8*)&Ks[ct * 16 + l16][ks * 32 + quad * 8];
                sc[ct] = __builtin_amdgcn_mfma_f32_16x16x32_bf16(qf[ks], kf, sc[ct], 0, 0, 0);
            }
        }
        int rowbase = qtile * 64 + wave * 16 + quad * 4;
#pragma unroll
        for (int ct = 0; ct < 4; ct++) {
            int col = kt * 64 + ct * 16 + l16;
#pragma unroll
            for (int rr = 0; rr < 4; rr++) {
                float x = sc[ct][rr] * scale;
                sc[ct][rr] = (col > rowbase + rr) ? NEG_S : x;
            }
        }
        float alpha[4];
#pragma unroll
        for (int rr = 0; rr < 4; rr++) {
            float mx = fmaxf(fmaxf(sc[0][rr], sc[1][rr]), fmaxf(sc[2][rr], sc[3][rr]));
            mx = fmaxf(mx, __shfl_xor(mx, 1));
            mx = fmaxf(mx, __shfl_xor(mx, 2));
            mx = fmaxf(mx, __shfl_xor(mx, 4));
            mx = fmaxf(mx, __shfl_xor(mx, 8));
            float mnew = fmaxf(mrow[rr], mx);
            alpha[rr] = exp2f((mrow[rr] - mnew) * LOG2E);
            mrow[rr] = mnew;
        }
#pragma unroll
        for (int rr = 0; rr < 4; rr++) {
            float ps = 0.f;
#pragma unroll
            for (int ct = 0; ct < 4; ct++) {
                float p = exp2f((sc[ct][rr] - mrow[rr]) * LOG2E);
                sc[ct][rr] = p;
                ps += p;
            }
            ps += __shfl_xor(ps, 1);
            ps += __shfl_xor(ps, 2);
            ps += __shfl_xor(ps, 4);
            ps += __shfl_xor(ps, 8);
            lrow[rr] = lrow[rr] * alpha[rr] + ps;
        }
#pragma unroll
        for (int c8 = 0; c8 < 8; c8++)
#pragma unroll
            for (int rr = 0; rr < 4; rr++) O[c8][rr] *= alpha[rr];

#pragma unroll
        for (int ct = 0; ct < 4; ct++)
#pragma unroll
            for (int rr = 0; rr < 4; rr++)
                Ps[wave][quad * 4 + rr][ct * 16 + l16] = f2bf(sc[ct][rr]);
        __syncthreads();

#pragma unroll
        for (int ka2 = 0; ka2 < 2; ka2++) {
            short8 pa = *(const short8*)&Ps[wave][l16][ka2 * 32 + quad * 8];
#pragma unroll
            for (int c8 = 0; c8 < 8; c8++) {
                short8 vf = *(const short8*)&Vt[c8 * 16 + l16][ka2 * 32 + quad * 8];
                O[c8] = __builtin_amdgcn_mfma_f32_16x16x32_bf16(pa, vf, O[c8], 0, 0, 0);
            }
        }
    }

#pragma unroll
    for (int rr = 0; rr < 4; rr++) {
        float inv = 1.f / lrow[rr];
        int lrw = blockIdx.x * 64 + wave * 16 + quad * 4 + rr;
#pragma unroll
        for (int c8 = 0; c8 < 8; c8++) {
            int d = c8 * 16 + l16;
            Omid[(size_t)lrw * E_ + h * D_ + d] = f2bf(O[c8][rr] * inv);
        }
    }
}

extern "C" void kernel_launch(void* const* d_in, const int* in_sizes, int n_in,
                              void* d_out, int out_size, void* d_ws, size_t ws_size,
                              hipStream_t stream) {
    const float* x  = (const float*)d_in[0];
    const float* Wq = (const float*)d_in[1];
    const float* Wk = (const float*)d_in[2];
    const float* Wv = (const float*)d_in[3];
    const float* Wo = (const float*)d_in[4];

    float* out_attn = (float*)d_out;                              // (B,S,E) fp32
    float* out_k = out_attn + (size_t)B_ * H_ * S_ * D_;          // (B,H,S,D) fp32 pre-rope
    float* out_v = out_k + (size_t)B_ * H_ * S_ * D_;             // (B,H,S,D) fp32

    char* ws = (char*)d_ws;
    float* cosT = (float*)ws;
    float* sinT = cosT + S_ * (D_ / 2);
    size_t tab_bytes = 2u * S_ * (D_ / 2) * sizeof(float);        // 1 MB

    size_t krBytes  = (size_t)B_ * H_ * S_ * D_ * 2;              // 16.8 MB
    size_t wbBytes  = (size_t)E_ * E_ * 2;                        // 8.4 MB
    size_t midBytes = (size_t)B_ * S_ * E_ * 2;                   // 16.8 MB
    size_t needFast = tab_bytes + 2 * krBytes + wbBytes + midBytes; // ~59.8 MB

    hipLaunchKernelGGL(rope_tab, dim3(512), dim3(256), 0, stream, cosT, sinT);

    if (ws_size >= needFast) {
        // ---------------- fast path ----------------
        unsigned short* Kr  = (unsigned short*)(ws + tab_bytes);
        unsigned short* Vt  = Kr + (size_t)B_ * H_ * S_ * D_;
        unsigned short* Wb  = Vt + (size_t)B_ * H_ * S_ * D_;
        unsigned short* mid = Wb + (size_t)E_ * E_;
        unsigned short* xb    = (unsigned short*)out_attn;                       // [0,16.8M)
        unsigned short* q_tmp = (unsigned short*)(out_attn + (size_t)S_ * E_);   // [16.8,33.5M)

        hipLaunchKernelGGL(cvt_bf16, dim3(4096), dim3(256), 0, stream, x, xb, 1048576);

        hipLaunchKernelGGL(cvt_bf16, dim3(2048), dim3(256), 0, stream, Wq, Wb, 524288);
        hipLaunchKernelGGL(gemm128, dim3(32, 16), dim3(256), 0, stream, xb, Wb, (void*)q_tmp, 3);

        hipLaunchKernelGGL(cvt_bf16, dim3(2048), dim3(256), 0, stream, Wk, Wb, 524288);
        hipLaunchKernelGGL(gemm128, dim3(32, 16), dim3(256), 0, stream, xb, Wb, (void*)out_k, 1);
        hipLaunchKernelGGL(prep_k, dim3(4096), dim3(256), 0, stream, out_k, Kr, cosT, sinT);

        hipLaunchKernelGGL(cvt_bf16, dim3(2048), dim3(256), 0, stream, Wv, Wb, 524288);
        hipLaunchKernelGGL(gemm128, dim3(32, 16), dim3(256), 0, stream, xb, Wb, (void*)out_v, 1);
        hipLaunchKernelGGL(prep_v, dim3(32, 32), dim3(256), 0, stream, out_v, Vt);

        hipLaunchKernelGGL(cvt_bf16, dim3(2048), dim3(256), 0, stream, Wo, Wb, 524288);

        hipLaunchKernelGGL(attn_fast6, dim3(512, B_), dim3(256), 0, stream,
                           q_tmp, Kr, Vt, cosT, sinT, mid);
        hipLaunchKernelGGL(gemm128, dim3(32, 16), dim3(256), 0, stream, mid, Wb,
                           (void*)out_attn, 0);
    } else {
        // ---------------- legacy fallback (previous passing version) -------
        unsigned short* q_tmp = (unsigned short*)(out_attn + (size_t)S_ * E_);
        unsigned short* mid = (unsigned short*)(ws + tab_bytes);
        size_t avail = ws_size > tab_bytes ? ws_size - tab_bytes : 0;
        int R = 64;
        for (int r = 2048; r >= 64; r >>= 1) {
            if ((size_t)r * E_ * 2 <= avail) { R = r; break; }
        }

        dim3 gg(64, 32);
        hipLaunchKernelGGL(gemm_bt, gg, dim3(256), 0, stream, (const void*)x, Wq, (void*)q_tmp, 0, 3);
        hipLaunchKernelGGL(gemm_bt, gg, dim3(256), 0, stream, (const void*)x, Wk, (void*)out_k, 0, 1);
        hipLaunchKernelGGL(gemm_bt, gg, dim3(256), 0, stream, (const void*)x, Wv, (void*)out_v, 0, 1);

        const size_t bhsd = (size_t)H_ * S_ * D_;
        for (int b = 0; b < B_; b++) {
            const unsigned short* qb = q_tmp + (size_t)b * S_ * E_;
            for (int c = 0; c < S_ / 64; c += R / 64) {
                hipLaunchKernelGGL(attn_fwd, dim3(R / 64, H_), dim3(256), 0, stream,
                                   qb, out_k + b * bhsd, out_v + b * bhsd,
                                   cosT, sinT, mid, c);
                hipLaunchKernelGGL(gemm_bt, dim3(R / 64, 32), dim3(256), 0, stream,
                                   (const void*)mid, Wo,
                                   (void*)(out_attn + ((size_t)b * S_ + c * 64) * E_), 1, 0);
            }
        }
    }
}